// Round 17
// baseline (5128.548 us; speedup 1.0000x reference)
//
#include <hip/hip_runtime.h>

typedef unsigned int u32;
typedef short bf16x8 __attribute__((ext_vector_type(8)));
typedef float f32x4 __attribute__((ext_vector_type(4)));
typedef u32 __attribute__((address_space(1))) u32g;
typedef u32 __attribute__((address_space(3))) u32l;

#define B_  4
#define N_  9216
#define D_  512
#define NH_ 8
#define HD_ 64
#define L_  64
#define HH_ 96
#define MT_ 36864
#define SCALE_ 0.125f
#define NS_ 4   /* s3 splits */

__device__ __forceinline__ float bf2f(unsigned short u) {
    union { u32 i; float f; } c; c.i = ((u32)u) << 16; return c.f;
}
__device__ __forceinline__ unsigned short f2bf(float f) {
    u32 x = __float_as_uint(f);
    return (unsigned short)((x + 0x7fffu + ((x >> 16) & 1u)) >> 16);
}
__device__ __forceinline__ int lm_idx(int l){ return (l * 9215) / 63; }
__device__ __forceinline__ u32 pk2(float a, float b){ return (u32)f2bf(a) | ((u32)f2bf(b) << 16); }

// ---------------------------------------------------------------------------
// K0: weight prep — proj_w -> bf16 hi/lo; mlp w1/w2 -> bf16.
// ---------------------------------------------------------------------------
#define PJW_N  262144
#define MLPW_N 1048576
__global__ __launch_bounds__(256)
void prep_weights(const float* __restrict__ pjw,
                  const float* __restrict__ w1, const float* __restrict__ w2,
                  unsigned short* __restrict__ pwh, unsigned short* __restrict__ pwl,
                  unsigned short* __restrict__ w1b, unsigned short* __restrict__ w2b)
{
    const int total = PJW_N + MLPW_N + MLPW_N;
    for (int i = blockIdx.x * 256 + threadIdx.x; i < total; i += gridDim.x * 256) {
        if (i < PJW_N) {
            float v = pjw[i]; unsigned short h = f2bf(v);
            pwh[i] = h; pwl[i] = f2bf(v - bf2f(h));
        } else if (i < PJW_N + MLPW_N) {
            int j = i - PJW_N;
            w1b[j] = f2bf(w1[j]);
        } else {
            int j = i - PJW_N - MLPW_N;
            w2b[j] = f2bf(w2[j]);
        }
    }
}

// ---------------------------------------------------------------------------
// K1: PPEG + residual + LN(ppeg) -> x1 (f32) + norm1 stats.  LDS 64 B.
// ---------------------------------------------------------------------------
__global__ __launch_bounds__(512)
void ppeg_ln_kernel(const float* __restrict__ x,
                    const float* __restrict__ c1w, const float* __restrict__ c1b,
                    const float* __restrict__ c2w, const float* __restrict__ c2b,
                    const float* __restrict__ c3w, const float* __restrict__ c3b,
                    const float* __restrict__ pg, const float* __restrict__ pb,
                    float* __restrict__ x1, float* __restrict__ stats)
{
    const int b = blockIdx.x / HH_;
    const int h = blockIdx.x % HH_;
    const int d = threadIdx.x;
    const int tid = threadIdx.x;

    float wtap[49];
    #pragma unroll
    for (int i = 0; i < 49; ++i) wtap[i] = c3w[d * 49 + i];
    #pragma unroll
    for (int ky = 0; ky < 5; ++ky)
        #pragma unroll
        for (int kx = 0; kx < 5; ++kx)
            wtap[(ky + 1) * 7 + (kx + 1)] += c2w[d * 25 + ky * 5 + kx];
    #pragma unroll
    for (int ky = 0; ky < 3; ++ky)
        #pragma unroll
        for (int kx = 0; kx < 3; ++kx)
            wtap[(ky + 2) * 7 + (kx + 2)] += c1w[d * 9 + ky * 3 + kx];

    const float bsum = c1b[d] + c2b[d] + c3b[d];
    const float gpv = pg[d], bpv = pb[d];

    __shared__ float red[2][8];

    for (int w = 0; w < HH_; ++w) {
        float pos = bsum;
        float xc = 0.f;
        #pragma unroll
        for (int dy = -3; dy <= 3; ++dy) {
            int hh = h + dy;
            if (hh < 0 || hh >= HH_) continue;
            #pragma unroll
            for (int dx = -3; dx <= 3; ++dx) {
                int ww = w + dx;
                if (ww < 0 || ww >= HH_) continue;
                float xv = x[(size_t)(b * N_ + hh * HH_ + ww) * D_ + d];
                pos += xv * wtap[(dy + 3) * 7 + (dx + 3)];
                if (dy == 0 && dx == 0) xc = xv;
            }
        }
        float s = xc + pos;

        float sv = s, sq = s * s;
        #pragma unroll
        for (int o = 32; o > 0; o >>= 1) { sv += __shfl_down(sv, o); sq += __shfl_down(sq, o); }
        if ((tid & 63) == 0) { red[0][tid >> 6] = sv; red[1][tid >> 6] = sq; }
        __syncthreads();
        float tot = 0.f, totq = 0.f;
        #pragma unroll
        for (int i = 0; i < 8; ++i) { tot += red[0][i]; totq += red[1][i]; }
        __syncthreads();
        float mean = tot * (1.f / 512.f);
        float var  = totq * (1.f / 512.f) - mean * mean;
        float x1v = (s - mean) * rsqrtf(var + 1e-5f) * gpv + bpv;

        float sv2 = x1v, sq2 = x1v * x1v;
        #pragma unroll
        for (int o = 32; o > 0; o >>= 1) { sv2 += __shfl_down(sv2, o); sq2 += __shfl_down(sq2, o); }
        if ((tid & 63) == 0) { red[0][tid >> 6] = sv2; red[1][tid >> 6] = sq2; }
        __syncthreads();
        float tot2 = 0.f, totq2 = 0.f;
        #pragma unroll
        for (int i = 0; i < 8; ++i) { tot2 += red[0][i]; totq2 += red[1][i]; }
        __syncthreads();
        float m2 = tot2 * (1.f / 512.f);
        float v2 = totq2 * (1.f / 512.f) - m2 * m2;

        size_t row = (size_t)(b * N_ + h * HH_ + w);
        x1[row * D_ + d] = x1v;
        if (tid == 0) {
            stats[row * 2 + 0] = m2;
            stats[row * 2 + 1] = rsqrtf(v2 + 1e-5f);
        }
    }
}

// ---------------------------------------------------------------------------
// K2: f32 vector GEMM for q/k: out(b,h,n,d) = xn @ W[WROW0..+512]^T + b.
// ---------------------------------------------------------------------------
template<int WROW0>
__global__ __launch_bounds__(256)
void gemm_f32_ln(const float* __restrict__ X1, const float* __restrict__ stats,
                 const float* __restrict__ g1, const float* __restrict__ b1,
                 const float* __restrict__ qkvw, const float* __restrict__ qkvb,
                 float* __restrict__ out)
{
    __shared__ float xnS[64][33];
    __shared__ float wS[64][33];
    const int tid = threadIdx.x;
    const int n0 = blockIdx.x * 64;
    const int m0 = blockIdx.y * 64;
    const int tm = tid >> 4, tn = tid & 15;

    float acc[4][4];
    #pragma unroll
    for (int i = 0; i < 4; ++i)
        #pragma unroll
        for (int j = 0; j < 4; ++j) acc[i][j] = 0.f;

    for (int k0 = 0; k0 < 512; k0 += 32) {
        #pragma unroll
        for (int e = 0; e < 8; ++e) {
            int i = tid + 256 * e;
            int row = i >> 5, kk = i & 31;
            float xv = X1[(size_t)(m0 + row) * 512 + k0 + kk];
            float mean = stats[(m0 + row) * 2], rs = stats[(m0 + row) * 2 + 1];
            xnS[row][kk] = (xv - mean) * rs * g1[k0 + kk] + b1[k0 + kk];
            wS[row][kk] = qkvw[(size_t)(WROW0 + n0 + row) * 512 + k0 + kk];
        }
        __syncthreads();
        for (int kk = 0; kk < 32; ++kk) {
            float a_[4], b_[4];
            #pragma unroll
            for (int i = 0; i < 4; ++i) a_[i] = xnS[tm * 4 + i][kk];
            #pragma unroll
            for (int j = 0; j < 4; ++j) b_[j] = wS[tn * 4 + j][kk];
            #pragma unroll
            for (int i = 0; i < 4; ++i)
                #pragma unroll
                for (int j = 0; j < 4; ++j) acc[i][j] += a_[i] * b_[j];
        }
        __syncthreads();
    }
    #pragma unroll
    for (int i = 0; i < 4; ++i) {
        #pragma unroll
        for (int j = 0; j < 4; ++j) {
            int gm = m0 + tm * 4 + i, gc = n0 + tn * 4 + j;
            int b = gm / N_, n = gm - b * N_;
            int h = gc >> 6, d = gc & 63;
            out[(((size_t)b * NH_ + h) * N_ + n) * HD_ + d] = acc[i][j] + qkvb[WROW0 + gc];
        }
    }
}

// ---------------------------------------------------------------------------
// K3: extract landmarks from q/k buffers.  grid 32.
// ---------------------------------------------------------------------------
__global__ __launch_bounds__(256)
void extract_lm(const float* __restrict__ q, const float* __restrict__ k,
                float* __restrict__ qlf, float* __restrict__ klf,
                double* __restrict__ ql64, double* __restrict__ kl64)
{
    const int bh = blockIdx.x, tid = threadIdx.x;
    const int b = bh >> 3, h = bh & 7;
    for (int i = tid; i < 4096; i += 256) {
        int l = i >> 6, d = i & 63;
        size_t src = (((size_t)b * NH_ + h) * N_ + lm_idx(l)) * HD_ + d;
        float qv = q[src], kv = k[src];
        size_t dst = (size_t)bh * 4096 + i;
        qlf[dst] = qv; klf[dst] = kv;
        ql64[dst] = (double)qv; kl64[dst] = (double)kv;
    }
}

// ---------------------------------------------------------------------------
// K4: k2 = softmax f64; TRUNCATED PINV via Jacobi eigensolver of A^T A.
// rcond = 10*64*eps_f32 = 7.62939453125e-5 (jax pinv default).
// 512 THREADS (8 waves, 4 pairs/wave): per-lane param chain for pair
// wv*4+(lane&3) (4 parallel chains/wave), __shfl broadcast (register,
// wave-synchronous); rotations wave-per-pair conflict-free, ILP-batched;
// NO barrier between params and row phase (param reads touch only own
// pairs' rows, disjoint from other waves' row writes).  2 barriers/round.
// Same IEEE ops on same operands, disjoint-pair order-independent
// -> bit-identical output.  LDS ~101.5 KB.
// ---------------------------------------------------------------------------
__global__ __launch_bounds__(512)
void k2pinv_kernel(const double* __restrict__ ql64, const double* __restrict__ kl64,
                   double* __restrict__ k2inv)
{
    const int bh = blockIdx.x;
    const int tid = threadIdx.x;
    const int lane = tid & 63, wv = tid >> 6;   // 8 waves
    __shared__ double A[64][65];
    __shared__ double G[64][65];
    __shared__ double V[64][65];
    __shared__ double wS[64];
    __shared__ double lmaxS;

    for (int i = tid; i < 4096; i += 512) {
        int l = i >> 6, m = i & 63;
        const double* qp = ql64 + (size_t)bh * 4096 + l * 64;
        const double* kp = kl64 + (size_t)bh * 4096 + m * 64;
        double s = 0.0;
        for (int d = 0; d < 64; ++d) s += qp[d] * kp[d];
        A[l][m] = s * 0.125;
    }
    __syncthreads();
    if (tid < 64) {
        double mx = -1e300;
        for (int j = 0; j < 64; ++j) mx = fmax(mx, A[tid][j]);
        double sm = 0.0;
        for (int j = 0; j < 64; ++j) { double e = exp(A[tid][j] - mx); A[tid][j] = e; sm += e; }
        double inv = 1.0 / sm;
        for (int j = 0; j < 64; ++j) A[tid][j] *= inv;
        A[tid][tid] += 1e-6;
    }
    __syncthreads();
    for (int e = tid; e < 4096; e += 512) {
        int i = e >> 6, j = e & 63;
        double s = 0.0;
        for (int l = 0; l < 64; ++l) s += A[l][i] * A[l][j];
        G[i][j] = s;
        V[i][j] = (i == j) ? 1.0 : 0.0;
    }
    __syncthreads();
    for (int sweep = 0; sweep < 10; ++sweep) {
        for (int r = 0; r < 63; ++r) {
            // per-lane param chain for pair wv*4 + (lane&3): 4 parallel
            // chains per wave, computed redundantly across lane groups.
            double c, s;
            {
                int idx = wv * 4 + (lane & 3);
                int p, q;
                if (idx == 0) { p = 63; q = r; }
                else { p = (r + idx) % 63; q = (r - idx + 63) % 63; }
                double app = G[p][p], aqq = G[q][q], apq = G[p][q];
                c = 1.0; s = 0.0;
                if (fabs(apq) > 1e-200) {
                    double tau = (aqq - app) / (2.0 * apq);
                    double tt = ((tau >= 0.0) ? 1.0 : -1.0) / (fabs(tau) + sqrt(1.0 + tau * tau));
                    c = 1.0 / sqrt(1.0 + tt * tt);
                    s = tt * c;
                }
            }
            // pair indices for this wave's 4 pairs (cheap magic-mul modulo)
            int pA[4], qA[4];
            double cA[4], sA[4];
            #pragma unroll
            for (int t = 0; t < 4; ++t) {
                int idx2 = wv * 4 + t;
                if (idx2 == 0) { pA[t] = 63; qA[t] = r; }
                else { pA[t] = (r + idx2) % 63; qA[t] = (r - idx2 + 63) % 63; }
                cA[t] = __shfl(c, t);
                sA[t] = __shfl(s, t);
            }
            // row rotations (lane = column), ILP-batched; no barrier needed
            // before this: param reads hit only this wave's pair rows.
            {
                double gp[4], gq[4];
                #pragma unroll
                for (int t = 0; t < 4; ++t) { gp[t] = G[pA[t]][lane]; gq[t] = G[qA[t]][lane]; }
                #pragma unroll
                for (int t = 0; t < 4; ++t) {
                    G[pA[t]][lane] = cA[t] * gp[t] - sA[t] * gq[t];
                    G[qA[t]][lane] = sA[t] * gp[t] + cA[t] * gq[t];
                }
            }
            __syncthreads();
            // col rotations + V accumulation (lane = row), ILP-batched
            {
                double gp[4], gq[4], vp[4], vq[4];
                #pragma unroll
                for (int t = 0; t < 4; ++t) { gp[t] = G[lane][pA[t]]; gq[t] = G[lane][qA[t]]; }
                #pragma unroll
                for (int t = 0; t < 4; ++t) { vp[t] = V[lane][pA[t]]; vq[t] = V[lane][qA[t]]; }
                #pragma unroll
                for (int t = 0; t < 4; ++t) {
                    G[lane][pA[t]] = cA[t] * gp[t] - sA[t] * gq[t];
                    G[lane][qA[t]] = sA[t] * gp[t] + cA[t] * gq[t];
                }
                #pragma unroll
                for (int t = 0; t < 4; ++t) {
                    V[lane][pA[t]] = cA[t] * vp[t] - sA[t] * vq[t];
                    V[lane][qA[t]] = sA[t] * vp[t] + cA[t] * vq[t];
                }
            }
            __syncthreads();
        }
    }
    if (tid == 0) {
        double lm = 0.0;
        for (int j = 0; j < 64; ++j) lm = fmax(lm, G[j][j]);
        lmaxS = lm;
    }
    __syncthreads();
    if (tid < 64) {
        const double rc = 7.62939453125e-5;
        double cut = rc * rc * lmaxS;
        double l = G[tid][tid];
        wS[tid] = (l > cut) ? (1.0 / l) : 0.0;
    }
    __syncthreads();
    for (int e = tid; e < 4096; e += 512) {
        int i = e >> 6, j = e & 63;
        double s = 0.0;
        for (int m = 0; m < 64; ++m) s += V[i][m] * wS[m] * V[j][m];
        G[i][j] = s;
    }
    __syncthreads();
    for (int e = tid; e < 4096; e += 512) {
        int i = e >> 6, j = e & 63;
        double s = 0.0;
        for (int m = 0; m < 64; ++m) s += G[i][m] * A[j][m];
        k2inv[(size_t)bh * 4096 + e] = s;
    }
}

// ---------------------------------------------------------------------------
// K5: s3_U — U = P3 @ xn.  Spill-free, conflict-free LDS.  LDS 35,584 B.
// grid (NS_, 32, 4), 256 thr.
// ---------------------------------------------------------------------------
__global__ __launch_bounds__(256)
void s3_u_kernel(const float* __restrict__ qlf, const float* __restrict__ k,
                 const float* __restrict__ X1, const float* __restrict__ stats,
                 const float* __restrict__ g1, const float* __restrict__ b1,
                 float* __restrict__ Up, float* __restrict__ sp)
{
    const int s = blockIdx.x;
    const int bh = blockIdx.y;
    const int dq = blockIdx.z;
    const int tid = threadIdx.x;
    const int b = bh >> 3;
    __shared__ float qlS[64][68];
    __shared__ float kS[16][68];
    __shared__ float S[64][17];
    __shared__ float xnS[16][132];
    __shared__ float gS[128], bS[128];
    const size_t kbase = (size_t)bh * N_ * HD_;
    const int f0 = dq * 128;

    for (int i = tid; i < 4096; i += 256) qlS[i >> 6][i & 63] = qlf[(size_t)bh * 4096 + i];
    if (tid < 128) { gS[tid] = g1[f0 + tid]; bS[tid] = b1[f0 + tid]; }

    const int lp = tid >> 3;
    const int fq = tid & 7;
    f32x4 acc0[4], acc1[4];
    #pragma unroll
    for (int j = 0; j < 4; ++j) { acc0[j] = (f32x4){0,0,0,0}; acc1[j] = (f32x4){0,0,0,0}; }
    float sacc0 = 0.f, sacc1 = 0.f;

    const int nchunks = (N_ / NS_) / 16;
    for (int c = 0; c < nchunks; ++c) {
        const int n0 = s * (N_ / NS_) + c * 16;
        __syncthreads();
        {
            int i = tid * 4;
            int n = i >> 6, d = i & 63;
            float4 v = *(const float4*)(k + kbase + (size_t)(n0 + n) * HD_ + d);
            kS[n][d + 0] = v.x; kS[n][d + 1] = v.y; kS[n][d + 2] = v.z; kS[n][d + 3] = v.w;
        }
        {
            int i = tid * 8;
            int r = i >> 7, fl = i & 127;
            int gm = b * N_ + n0 + r;
            float mean = stats[gm * 2], rs = stats[gm * 2 + 1];
            const float* xp = X1 + (size_t)gm * 512 + f0 + fl;
            float4 v0 = *(const float4*)(xp);
            float4 v1 = *(const float4*)(xp + 4);
            float xv[8] = {v0.x, v0.y, v0.z, v0.w, v1.x, v1.y, v1.z, v1.w};
            #pragma unroll
            for (int e = 0; e < 8; ++e) {
                int f = fl + e;
                float val = (xv[e] - mean) * rs * gS[f] + bS[f];
                int g = f >> 2;
                int slot = ((g & 3) << 3) | (g >> 2);
                xnS[r][slot * 4 + (f & 3)] = val;
            }
        }
        __syncthreads();
        {
            const int n = tid & 15;
            const int l0 = (tid >> 4) << 2;
            const f32x4* kr4 = (const f32x4*)&kS[n][0];
            const f32x4* q0 = (const f32x4*)&qlS[l0 + 0][0];
            const f32x4* q1 = (const f32x4*)&qlS[l0 + 1][0];
            const f32x4* q2 = (const f32x4*)&qlS[l0 + 2][0];
            const f32x4* q3 = (const f32x4*)&qlS[l0 + 3][0];
            float s0 = 0.f, s1 = 0.f, s2 = 0.f, s3 = 0.f;
            #pragma unroll
            for (int d4 = 0; d4 < 16; ++d4) {
                f32x4 kv = kr4[d4];
                f32x4 a0 = q0[d4], a1 = q1[d4], a2 = q2[d4], a3 = q3[d4];
                s0 += a0.x * kv.x + a0.y * kv.y + a0.z * kv.z + a0.w * kv.w;
                s1 += a1.x * kv.x + a1.y * kv.y + a1.z * kv.z + a1.w * kv.w;
                s2 += a2.x * kv.x + a2.y * kv.y + a2.z * kv.z + a2.w * kv.w;
                s3 += a3.x * kv.x + a3.y * kv.y + a3.z * kv.z + a3.w * kv.w;
            }
            S[l0 + 0][n] = expf(s0 * SCALE_);
            S[l0 + 1][n] = expf(s1 * SCALE_);
            S[l0 + 2][n] = expf(s2 * SCALE_);
            S[l0 + 3][n] = expf(s3 * SCALE_);
        }
        __syncthreads();
        for (int n = 0; n < 16; ++n) {
            float p0 = S[2 * lp + 0][n];
            float p1 = S[2 * lp + 1][n];
            const f32x4* xr = (const f32x4*)&xnS[n][0];
            #pragma unroll
            for (int j = 0; j < 4; ++j) {
                f32x4 xv = xr[fq + 8 * j];
                acc0[j].x += p0 * xv.x; acc0[j].y += p0 * xv.y;
                acc0[j].z += p0 * xv.z; acc0[j].w += p0 * xv.w;
                acc1[j].x += p1 * xv.x; acc1[j].y += p1 * xv.y;
                acc1[j].z += p1 * xv.z; acc1[j].w += p1 * xv.w;
            }
            if (dq == 0 && fq == 0) { sacc0 += p0; sacc1 += p1; }
        }
    }
    {
        size_t ubase = (((size_t)bh * NS_ + s) * 64) * 512;
        float4* u0 = (float4*)(Up + ubase + (size_t)(2 * lp + 0) * 512 + f0 + fq * 16);
        float4* u1 = (float4*)(Up + ubase + (size_t)(2 * lp + 1) * 512 + f0 + fq * 16);
        #pragma unroll
        for (int j = 0; j < 4; ++j) {
            u0[j] = (float4){acc0[j].x, acc0[j].y, acc0[j].z, acc0[j].w};
            u1[j] = (float4){acc1[j].x, acc1[j].y, acc1[j].z, acc1[j].w};
        }
    }
    if (dq == 0 && fq == 0) {
        sp[((size_t)bh * NS_ + s) * 64 + 2 * lp + 0] = sacc0;
        sp[((size_t)bh * NS_ + s) * 64 + 2 * lp + 1] = sacc1;
    }
}

// ---------------------------------------------------------------------------
// K6a: Un = (sum_s Up) / denom.  grid 32.
// ---------------------------------------------------------------------------
__global__ __launch_bounds__(256)
void combine_u_kernel(const float* __restrict__ Up, const float* __restrict__ sp,
                      float* __restrict__ Un)
{
    const int bh = blockIdx.x, tid = threadIdx.x;
    __shared__ float dro[64];
    if (tid < 64) {
        float d = 0.f;
        for (int s = 0; s < NS_; ++s) d += sp[((size_t)bh * NS_ + s) * 64 + tid];
        dro[tid] = d;
    }
    __syncthreads();
    for (int i = tid; i < 64 * 512; i += 256) {
        int l = i >> 9;
        float a = 0.f;
        for (int s = 0; s < NS_; ++s) a += Up[(((size_t)bh * NS_ + s) * 64) * 512 + i];
        Un[(size_t)bh * 64 * 512 + i] = a / dro[l];
    }
}

// ---------------------------------------------------------------------------
// K6b: Tn = Un @ Wv_head^T + bv.  grid 32.
// ---------------------------------------------------------------------------
__global__ __launch_bounds__(256)
void tn_kernel(const float* __restrict__ Un, const float* __restrict__ qkvw,
               const float* __restrict__ qkvb, float* __restrict__ Tn)
{
    const int bh = blockIdx.x, tid = threadIdx.x;
    const int h = bh & 7;
    const int l = tid >> 2, d0 = (tid & 3) * 16;
    const float* un = Un + (size_t)bh * 64 * 512 + l * 512;
    for (int j = 0; j < 16; ++j) {
        int d = d0 + j;
        const float* wv = qkvw + (size_t)(1024 + h * 64 + d) * 512;
        float t = 0.f;
        for (int f = 0; f < 512; ++f) t += un[f] * wv[f];
        Tn[(size_t)bh * 4096 + l * 64 + d] = t + qkvb[1024 + h * 64 + d];
    }
}

// ---------------------------------------------------------------------------
// K6c: W2 = k2pinv @ Tn.  grid 32.  LDS 16 KB.
// ---------------------------------------------------------------------------
__global__ __launch_bounds__(256)
void combine_b_kernel(const float* __restrict__ Tn, const double* __restrict__ k2inv,
                      float* __restrict__ W2)
{
    const int bh = blockIdx.x, tid = threadIdx.x;
    __shared__ float Tl[64][64];
    for (int i = tid; i < 4096; i += 256) Tl[i >> 6][i & 63] = Tn[(size_t)bh * 4096 + i];
    __syncthreads();
    const int l = tid >> 2, d0 = (tid & 3) * 16;
    float o[16];
    #pragma unroll
    for (int j = 0; j < 16; ++j) o[j] = 0.f;
    const double* kr = k2inv + (size_t)bh * 4096 + l * 64;
    for (int j2 = 0; j2 < 64; ++j2) {
        float a = (float)kr[j2];
        const float* tr = &Tl[j2][d0];
        #pragma unroll
        for (int j = 0; j < 16; ++j) o[j] += a * tr[j];
    }
    float* wp = W2 + (size_t)bh * 4096 + l * 64 + d0;
    #pragma unroll
    for (int j = 0; j < 16; ++j) wp[j] = o[j];
}

// ---------------------------------------------------------------------------
// K7: att = softmax(q·kl^T/8) @ W2 -> bf16 hi/lo.  LDS 32768 B.
// ---------------------------------------------------------------------------
__global__ __launch_bounds__(256)
void k1pv_kernel(const float* __restrict__ q, const float* __restrict__ klf,
                 const float* __restrict__ W2,
                 unsigned short* __restrict__ atth, unsigned short* __restrict__ attl)
{
    const int nc = blockIdx.x;
    const int bh = blockIdx.y;
    const int tid = threadIdx.x;
    __shared__ float klS[64][64];
    __shared__ float W2S[64][64];
    const size_t base = (size_t)bh * N_ * HD_;
    for (int i = tid; i < 4096; i += 256) {
        klS[i >> 6][i & 63] = klf[(size_t)bh * 4096 + i];
        W2S[i >> 6][i & 63] = W2[(size_t)bh * 4096 + i];
    }
    __syncthreads();
    const int n = nc * 256 + tid;
    float qf[64];
    const float4* qr = (const float4*)(q + base + (size_t)n * HD_);
    #pragma unroll
    for (int j = 0; j < 16; ++j) { float4 u = qr[j]; qf[j*4]=u.x; qf[j*4+1]=u.y; qf[j*4+2]=u.z; qf[j*4+3]=u.w; }
    float s[64];
    #pragma unroll
    for (int l = 0; l < 64; ++l) {
        const f32x4* kl4 = (const f32x4*)&klS[l][0];
        float t = 0.f;
        #pragma unroll
        for (int d4 = 0; d4 < 16; ++d4) {
            f32x4 w4 = kl4[d4];
            t += w4.x * qf[d4*4] + w4.y * qf[d4*4+1] + w4.z * qf[d4*4+2] + w4.w * qf[d4*4+3];
        }
        s[l] = t * SCALE_;
    }
    float mx = -1e30f;
    #pragma unroll
    for (int l = 0; l < 64; ++l) mx = fmaxf(mx, s[l]);
    float sum = 0.f;
    #pragma unroll
    for (int l = 0; l < 64; ++l) { s[l] = expf(s[l] - mx); sum += s[l]; }
    float inv = 1.f / sum;
    float acc[64];
    #pragma unroll
    for (int d2 = 0; d2 < 64; ++d2) acc[d2] = 0.f;
    #pragma unroll
    for (int l = 0; l < 64; ++l) {
        float p = s[l] * inv;
        const f32x4* w4p = (const f32x4*)&W2S[l][0];
        #pragma unroll
        for (int d4 = 0; d4 < 16; ++d4) {
            f32x4 w4 = w4p[d4];
            acc[d4*4+0] += p * w4.x; acc[d4*4+1] += p * w4.y;
            acc[d4*4+2] += p * w4.z; acc[d4*4+3] += p * w4.w;
        }
    }
    unsigned short* oh = atth + base + (size_t)n * HD_;
    unsigned short* ol = attl + base + (size_t)n * HD_;
    #pragma unroll
    for (int j = 0; j < 8; ++j) {
        float hv[8], lv[8];
        #pragma unroll
        for (int e = 0; e < 8; ++e) {
            float a = acc[j * 8 + e];
            unsigned short hb = f2bf(a);
            hv[e] = bf2f(hb);
            lv[e] = a - hv[e];
        }
        uint4 uh, ul;
        uh.x = pk2(hv[0], hv[1]); uh.y = pk2(hv[2], hv[3]);
        uh.z = pk2(hv[4], hv[5]); uh.w = pk2(hv[6], hv[7]);
        ul.x = pk2(lv[0], lv[1]); ul.y = pk2(lv[2], lv[3]);
        ul.z = pk2(lv[4], lv[5]); ul.w = pk2(lv[6], lv[7]);
        ((uint4*)oh)[j] = uh;
        ((uint4*)ol)[j] = ul;
    }
}

// ---------------------------------------------------------------------------
// K8: proj GEMM — split-precision MFMA (3-pass bf16 hi/lo), 128x64, BK=32.
// ---------------------------------------------------------------------------
__global__ __launch_bounds__(256)
void gemm_proj(const unsigned short* __restrict__ Aa, const unsigned short* __restrict__ Ab,
               const unsigned short* __restrict__ Wh, const unsigned short* __restrict__ Wl,
               const float* __restrict__ bias, float* __restrict__ fo0)
{
    __shared__ __align__(16) char AsH[8192];
    __shared__ __align__(16) char AsL[8192];
    __shared__ __align__(16) char BsH[4096];
    __shared__ __align__(16) char BsL[4096];
    const int tid = threadIdx.x;
    const int wv = tid >> 6, lane = tid & 63;
    const int wm = wv >> 1, wn = wv & 1;
    const int n0 = blockIdx.x * 64;
    const int m0 = blockIdx.y * 128;

    f32x4 acc[4][2];
    #pragma unroll
    for (int i = 0; i < 4; ++i)
        #pragma unroll
        for (int j = 0; j < 2; ++j) acc[i][j] = (f32x4){0.f, 0.f, 0.f, 0.f};

    for (int k0 = 0; k0 < 512; k0 += 32) {
        {
            int row = wv * 16 + (lane >> 2);
            int sl = lane & 3;
            int kk = k0 + ((sl ^ (row & 3)) << 3);
            const unsigned short* s0 = Wh + (size_t)(n0 + row) * 512 + kk;
            __builtin_amdgcn_global_load_lds((const u32g*)s0, (u32l*)(BsH + wv * 1024), 16, 0, 0);
            const unsigned short* s1 = Wl + (size_t)(n0 + row) * 512 + kk;
            __builtin_amdgcn_global_load_lds((const u32g*)s1, (u32l*)(BsL + wv * 1024), 16, 0, 0);
        }
        #pragma unroll
        for (int t = 0; t < 2; ++t) {
            int row = wv * 32 + t * 16 + (lane >> 2);
            int sl = lane & 3;
            int kk = k0 + ((sl ^ (row & 3)) << 3);
            int m = m0 + row;
            int b = m / N_; int n = m - b * N_; int hh = kk >> 6; int dd = kk & 63;
            size_t adr = (((size_t)b * NH_ + hh) * N_ + n) * HD_ + dd;
            __builtin_amdgcn_global_load_lds((const u32g*)(Aa + adr),
                                             (u32l*)(AsH + wv * 2048 + t * 1024), 16, 0, 0);
            __builtin_amdgcn_global_load_lds((const u32g*)(Ab + adr),
                                             (u32l*)(AsL + wv * 2048 + t * 1024), 16, 0, 0);
        }
        __syncthreads();
        bf16x8 afh[4], afl[4], bfh[2], bfl[2];
        #pragma unroll
        for (int mf = 0; mf < 4; ++mf) {
            int r = wm * 64 + mf * 16 + (lane & 15);
            int ps = (lane >> 4) ^ (r & 3);
            afh[mf] = *(const bf16x8*)(AsH + r * 64 + ps * 16);
            afl[mf] = *(const bf16x8*)(AsL + r * 64 + ps * 16);
        }
        #pragma unroll
        for (int nf = 0; nf < 2; ++nf) {
            int r = wn * 32 + nf * 16 + (lane & 15);
            int ps = (lane >> 4) ^ (r & 3);
            bfh[nf] = *(const bf16x8*)(BsH + r * 64 + ps * 16);
            bfl[nf] = *(const bf16x8*)(BsL + r * 64 + ps * 16);
        }
        #pragma unroll
        for (int mf = 0; mf < 4; ++mf)
            #pragma unroll
            for (int nf = 0; nf < 2; ++nf) {
                acc[mf][nf] = __builtin_amdgcn_mfma_f32_16x16x32_bf16(afh[mf], bfh[nf], acc[mf][nf], 0, 0, 0);
                acc[mf][nf] = __builtin_amdgcn_mfma_f32_16x16x32_bf16(afh[mf], bfl[nf], acc[mf][nf], 0, 0, 0);
                acc[mf][nf] = __builtin_amdgcn_mfma_f32_16x16x32_bf16(afl[mf], bfh[nf], acc[mf][nf], 0, 0, 0);
            }
        __syncthreads();
    }

    const int lc = lane & 15, lr4 = (lane >> 4) * 4;
    float bcol[2];
    #pragma unroll
    for (int nf = 0; nf < 2; ++nf)
        bcol[nf] = bias[n0 + wn * 32 + nf * 16 + lc];

    #pragma unroll
    for (int mf = 0; mf < 4; ++mf) {
        #pragma unroll
        for (int nf = 0; nf < 2; ++nf) {
            #pragma unroll
            for (int i = 0; i < 4; ++i) {
                int gm = m0 + wm * 64 + mf * 16 + lr4 + i;
                int gn = n0 + wn * 32 + nf * 16 + lc;
                fo0[(size_t)gm * 512 + gn] = acc[mf][nf][i] + bcol[nf];
            }
        }
    }
}

// ---------------------------------------------------------------------------
// K9: resid — x2 = x1 + pjo (in-place on pjo); xn2 = bf16(LN(x2, norm2)).
// ---------------------------------------------------------------------------
__global__ __launch_bounds__(256)
void resid_ln_kernel(const float* __restrict__ x1, float* __restrict__ pjo_x2,
                     const float* __restrict__ g, const float* __restrict__ bb,
                     unsigned short* __restrict__ xn2h)
{
    const int row = blockIdx.x, tid = threadIdx.x;
    const size_t base = (size_t)row * D_;
    float a0 = x1[base + tid]       + pjo_x2[base + tid];
    float a1 = x1[base + 256 + tid] + pjo_x2[base + 256 + tid];
    __shared__ float red[2][4];
    float sv = a0 + a1, sq = a0 * a0 + a1 * a1;
    #pragma unroll
    for (int o = 32; o > 0; o >>= 1) { sv += __shfl_down(sv, o); sq += __shfl_down(sq, o); }
    if ((tid & 63) == 0) { red[0][tid >> 6] = sv; red[1][tid >> 6] = sq; }
    __syncthreads();
    float tot = 0.f, totq = 0.f;
    #pragma unroll
    for (int i = 0; i < 4; ++i) { tot += red[0][i]; totq += red[1][i]; }
    float mean = tot * (1.f / 512.f);
    float var  = totq * (1.f / 512.f) - mean * mean;
    float rs = rsqrtf(var + 1e-5f);
    float o0 = (a0 - mean) * rs * g[tid]       + bb[tid];
    float o1 = (a1 - mean) * rs * g[256 + tid] + bb[256 + tid];
    pjo_x2[base + tid] = a0;
    pjo_x2[base + 256 + tid] = a1;
    xn2h[base + tid] = f2bf(o0);
    xn2h[base + 256 + tid] = f2bf(o1);
}

// ---------------------------------------------------------------------------
// K10: plain bf16 MFMA GEMM (MLP), 128x128 tile, BK=64.  LDS 32768 B.
// ---------------------------------------------------------------------------
#define E_GELU 0
#define E_ACC 1
#define E_FIN 2

template<int KLEN, int ALDA, int WLDA, int EPI, int OSTR>
__global__ __launch_bounds__(256)
void gemm_plain(const unsigned short* __restrict__ Aa,
                const unsigned short* __restrict__ Wh,
                int wrow0, int wcol0,
                const float* __restrict__ bias, int bias0,
                unsigned short* __restrict__ bo0, float* __restrict__ fo0,
                const unsigned short* __restrict__ accb, const float* __restrict__ resid)
{
    __shared__ __align__(16) char As[16384];
    __shared__ __align__(16) char Bs[16384];
    const int tid = threadIdx.x;
    const int wv = tid >> 6, lane = tid & 63;
    const int wm = wv >> 1, wn = wv & 1;
    const int n0 = blockIdx.x * 128;
    const int m0 = blockIdx.y * 128;
    const int rl = lane >> 3, sl = lane & 7;

    f32x4 acc[4][4];
    #pragma unroll
    for (int i = 0; i < 4; ++i)
        #pragma unroll
        for (int j = 0; j < 4; ++j) acc[i][j] = (f32x4){0.f, 0.f, 0.f, 0.f};

    for (int k0 = 0; k0 < KLEN; k0 += 64) {
        #pragma unroll
        for (int t = 0; t < 4; ++t) {
            int row = wv * 32 + t * 8 + rl;
            int slot = sl ^ (row & 7);
            const unsigned short* srcW = Wh + (size_t)(wrow0 + n0 + row) * WLDA + wcol0 + k0 + slot * 8;
            __builtin_amdgcn_global_load_lds((const u32g*)srcW, (u32l*)(Bs + wv * 4096 + t * 1024), 16, 0, 0);
            const unsigned short* srcA = Aa + (size_t)(m0 + row) * ALDA + k0 + slot * 8;
            __builtin_amdgcn_global_load_lds((const u32g*)srcA, (u32l*)(As + wv * 4096 + t * 1024), 16, 0, 0);
        }
        __syncthreads();
        #pragma unroll
        for (int ks = 0; ks < 2; ++ks) {
            bf16x8 af[4], bfr[4];
            #pragma unroll
            for (int mf = 0; mf < 4; ++mf) {
                int r = wm * 64 + mf * 16 + (lane & 15);
                int ps = (ks * 4 + (lane >> 4)) ^ (r & 7);
                af[mf] = *(const bf16x8*)(As + r * 128 + ps * 16);
            }
            #pragma unroll
            for (int nf = 0; nf < 4; ++nf) {
                int r = wn * 64 + nf * 16 + (lane & 15);
                int ps = (ks * 4 + (lane >> 4)) ^ (r & 7);
                bfr[nf] = *(const bf16x8*)(Bs + r * 128 + ps * 16);
            }
            #pragma unroll
            for (int mf = 0; mf < 4; ++mf)
                #pragma unroll
                for (int nf = 0; nf < 4; ++nf)
                    acc[mf][nf] = __builtin_amdgcn_mfma_f32_16x16x32_bf16(af[mf], bfr[nf], acc[mf][nf], 0, 0, 0);
        }
        __syncthreads();
    }

    const int lc = lane & 15, lr4 = (lane >> 4) * 4;
    float bcol[4];
    #pragma unroll
    for (int nf = 0; nf < 4; ++nf)
        bcol[nf] = bias ? bias[bias0 + n0 + wn * 64 + nf * 16 + lc] : 0.f;

    #pragma unroll
    for (int mf = 0; mf < 4; ++mf) {
        #pragma unroll
        for (int nf = 0; nf < 4; ++nf) {
            #pragma unroll
            for (int i = 0; i < 4; ++i) {
                int gm = m0 + wm * 64 + mf * 16 + lr4 + i;
                int gn = n0 + wn * 64 + nf * 16 + lc;
                float val = acc[mf][nf][i] + bcol[nf];
                if (EPI == E_GELU) {
                    float g = 0.5f * val * (1.f + erff(val * 0.70710678118f));
                    bo0[(size_t)gm * OSTR + gn] = f2bf(g);
                } else if (EPI == E_ACC) {
                    bo0[(size_t)gm * OSTR + gn] = f2bf(val);
                } else {
                    fo0[(size_t)gm * 512 + gn] = val + bf2f(accb[(size_t)gm * 512 + gn])
                                               + resid[(size_t)gm * 512 + gn];
                }
            }
        }
    }
}

// ---------------------------------------------------------------------------
extern "C" void kernel_launch(void* const* d_in, const int* in_sizes, int n_in,
                              void* d_out, int out_size, void* d_ws, size_t ws_size,
                              hipStream_t stream) {
    const float* x    = (const float*)d_in[0];
    const float* c1w  = (const float*)d_in[1];
    const float* c1b  = (const float*)d_in[2];
    const float* c2w  = (const float*)d_in[3];
    const float* c2b  = (const float*)d_in[4];
    const float* c3w  = (const float*)d_in[5];
    const float* c3b  = (const float*)d_in[6];
    const float* pg   = (const float*)d_in[7];
    const float* pb   = (const float*)d_in[8];
    const float* n1g  = (const float*)d_in[9];
    const float* n1b  = (const float*)d_in[10];
    const float* n2g  = (const float*)d_in[11];
    const float* n2b  = (const float*)d_in[12];
    const float* qkvw = (const float*)d_in[13];
    const float* qkvb = (const float*)d_in[14];
    const float* pjw  = (const float*)d_in[15];
    const float* pjb  = (const float*)d_in[16];
    const float* w1   = (const float*)d_in[17];
    const float* b1   = (const float*)d_in[18];
    const float* w2m  = (const float*)d_in[19];
    const float* b2m  = (const float*)d_in[20];

    char* ws = (char*)d_ws;
    char* RA = ws;
    char* RB = ws + 75497472;
    char* RC = ws + 150994944;
    char* R3 = ws + 226492416;
    unsigned short* pwh  = (unsigned short*)(R3 + 0);
    unsigned short* pwl  = (unsigned short*)(R3 + 524288);
    unsigned short* w1b  = (unsigned short*)(R3 + 1048576);
    unsigned short* w2b  = (unsigned short*)(R3 + 3145728);
    float*  stats = (float*)(R3 + 5242880);
    float*  qlf   = (float*)(R3 + 5537792);
    float*  klf   = (float*)(R3 + 6062080);
    double* ql64  = (double*)(R3 + 6586368);
    double* kl64  = (double*)(R3 + 7634944);
    double* k2i   = (double*)(R3 + 8683520);
    float*  W2    = (float*)(R3 + 9732096);
    float*  Tn    = (float*)(R3 + 10256384);
    float*  sp    = (float*)(R3 + 10780672);
    float*  Up    = (float*)(R3 + 10813440);
    float*  Un    = (float*)(R3 + 27590656);

    float* x1 = (float*)RA;
    float* kb = (float*)RB;
    float* qb = (float*)RC;
    unsigned short* atth = (unsigned short*)RB;
    unsigned short* attl = (unsigned short*)(RB + 37748736);
    float* pjo = (float*)RC;
    unsigned short* xn2  = (unsigned short*)RB;
    unsigned short* accb = (unsigned short*)(RB + 37748736);
    unsigned short* hbuf = (unsigned short*)RA;

    prep_weights<<<1024, 256, 0, stream>>>(pjw, w1, w2m, pwh, pwl, w1b, w2b);
    ppeg_ln_kernel<<<B_ * HH_, 512, 0, stream>>>(x, c1w, c1b, c2w, c2b, c3w, c3b,
                                                 pg, pb, x1, stats);
    gemm_f32_ln<512><<<dim3(8, 576), 256, 0, stream>>>(x1, stats, n1g, n1b, qkvw, qkvb, kb);
    gemm_f32_ln<0><<<dim3(8, 576), 256, 0, stream>>>(x1, stats, n1g, n1b, qkvw, qkvb, qb);
    extract_lm<<<32, 256, 0, stream>>>(qb, kb, qlf, klf, ql64, kl64);
    k2pinv_kernel<<<32, 512, 0, stream>>>(ql64, kl64, k2i);
    s3_u_kernel<<<dim3(NS_, 32, 4), 256, 0, stream>>>(qlf, kb, x1, stats, n1g, n1b, Up, sp);
    combine_u_kernel<<<32, 256, 0, stream>>>(Up, sp, Un);
    tn_kernel<<<32, 256, 0, stream>>>(Un, qkvw, qkvb, Tn);
    combine_b_kernel<<<32, 256, 0, stream>>>(Tn, k2i, W2);
    k1pv_kernel<<<dim3(36, 32), 256, 0, stream>>>(qb, klf, W2, atth, attl);
    gemm_proj<<<dim3(8, 288), 256, 0, stream>>>(atth, attl, pwh, pwl, pjb, pjo);
    resid_ln_kernel<<<MT_, 256, 0, stream>>>(x1, pjo, n2g, n2b, xn2);
    gemm_plain<512, 512, 512, E_GELU, 1024><<<dim3(8, 288), 256, 0, stream>>>(
        xn2, w1b, 0, 0, b1, 0, hbuf, nullptr, nullptr, nullptr);
    gemm_plain<1024, 1024, 2048, E_ACC, 512><<<dim3(4, 288), 256, 0, stream>>>(
        hbuf, w2b, 0, 0, nullptr, 0, accb, nullptr, nullptr, nullptr);
    gemm_plain<512, 512, 512, E_GELU, 1024><<<dim3(8, 288), 256, 0, stream>>>(
        xn2, w1b, 1024, 0, b1, 1024, hbuf, nullptr, nullptr, nullptr);
    gemm_plain<1024, 1024, 2048, E_FIN, 512><<<dim3(4, 288), 256, 0, stream>>>(
        hbuf, w2b, 0, 1024, b2m, 0, nullptr, (float*)d_out, accb, pjo);
}

// Round 18
// 4548.672 us; speedup vs baseline: 1.1275x; 1.1275x over previous
//
#include <hip/hip_runtime.h>

typedef unsigned int u32;
typedef short bf16x8 __attribute__((ext_vector_type(8)));
typedef float f32x4 __attribute__((ext_vector_type(4)));
typedef u32 __attribute__((address_space(1))) u32g;
typedef u32 __attribute__((address_space(3))) u32l;

#define B_  4
#define N_  9216
#define D_  512
#define NH_ 8
#define HD_ 64
#define L_  64
#define HH_ 96
#define MT_ 36864
#define SCALE_ 0.125f
#define NS_ 4   /* s3 splits */

__device__ __forceinline__ float bf2f(unsigned short u) {
    union { u32 i; float f; } c; c.i = ((u32)u) << 16; return c.f;
}
__device__ __forceinline__ unsigned short f2bf(float f) {
    u32 x = __float_as_uint(f);
    return (unsigned short)((x + 0x7fffu + ((x >> 16) & 1u)) >> 16);
}
__device__ __forceinline__ int lm_idx(int l){ return (l * 9215) / 63; }
__device__ __forceinline__ u32 pk2(float a, float b){ return (u32)f2bf(a) | ((u32)f2bf(b) << 16); }

// ---------------------------------------------------------------------------
// K0: weight prep — proj_w -> bf16 hi/lo; mlp w1/w2 -> bf16.
// ---------------------------------------------------------------------------
#define PJW_N  262144
#define MLPW_N 1048576
__global__ __launch_bounds__(256)
void prep_weights(const float* __restrict__ pjw,
                  const float* __restrict__ w1, const float* __restrict__ w2,
                  unsigned short* __restrict__ pwh, unsigned short* __restrict__ pwl,
                  unsigned short* __restrict__ w1b, unsigned short* __restrict__ w2b)
{
    const int total = PJW_N + MLPW_N + MLPW_N;
    for (int i = blockIdx.x * 256 + threadIdx.x; i < total; i += gridDim.x * 256) {
        if (i < PJW_N) {
            float v = pjw[i]; unsigned short h = f2bf(v);
            pwh[i] = h; pwl[i] = f2bf(v - bf2f(h));
        } else if (i < PJW_N + MLPW_N) {
            int j = i - PJW_N;
            w1b[j] = f2bf(w1[j]);
        } else {
            int j = i - PJW_N - MLPW_N;
            w2b[j] = f2bf(w2[j]);
        }
    }
}

// ---------------------------------------------------------------------------
// K1: PPEG + residual + LN(ppeg) -> x1 (f32) + norm1 stats.  LDS 64 B.
// ---------------------------------------------------------------------------
__global__ __launch_bounds__(512)
void ppeg_ln_kernel(const float* __restrict__ x,
                    const float* __restrict__ c1w, const float* __restrict__ c1b,
                    const float* __restrict__ c2w, const float* __restrict__ c2b,
                    const float* __restrict__ c3w, const float* __restrict__ c3b,
                    const float* __restrict__ pg, const float* __restrict__ pb,
                    float* __restrict__ x1, float* __restrict__ stats)
{
    const int b = blockIdx.x / HH_;
    const int h = blockIdx.x % HH_;
    const int d = threadIdx.x;
    const int tid = threadIdx.x;

    float wtap[49];
    #pragma unroll
    for (int i = 0; i < 49; ++i) wtap[i] = c3w[d * 49 + i];
    #pragma unroll
    for (int ky = 0; ky < 5; ++ky)
        #pragma unroll
        for (int kx = 0; kx < 5; ++kx)
            wtap[(ky + 1) * 7 + (kx + 1)] += c2w[d * 25 + ky * 5 + kx];
    #pragma unroll
    for (int ky = 0; ky < 3; ++ky)
        #pragma unroll
        for (int kx = 0; kx < 3; ++kx)
            wtap[(ky + 2) * 7 + (kx + 2)] += c1w[d * 9 + ky * 3 + kx];

    const float bsum = c1b[d] + c2b[d] + c3b[d];
    const float gpv = pg[d], bpv = pb[d];

    __shared__ float red[2][8];

    for (int w = 0; w < HH_; ++w) {
        float pos = bsum;
        float xc = 0.f;
        #pragma unroll
        for (int dy = -3; dy <= 3; ++dy) {
            int hh = h + dy;
            if (hh < 0 || hh >= HH_) continue;
            #pragma unroll
            for (int dx = -3; dx <= 3; ++dx) {
                int ww = w + dx;
                if (ww < 0 || ww >= HH_) continue;
                float xv = x[(size_t)(b * N_ + hh * HH_ + ww) * D_ + d];
                pos += xv * wtap[(dy + 3) * 7 + (dx + 3)];
                if (dy == 0 && dx == 0) xc = xv;
            }
        }
        float s = xc + pos;

        float sv = s, sq = s * s;
        #pragma unroll
        for (int o = 32; o > 0; o >>= 1) { sv += __shfl_down(sv, o); sq += __shfl_down(sq, o); }
        if ((tid & 63) == 0) { red[0][tid >> 6] = sv; red[1][tid >> 6] = sq; }
        __syncthreads();
        float tot = 0.f, totq = 0.f;
        #pragma unroll
        for (int i = 0; i < 8; ++i) { tot += red[0][i]; totq += red[1][i]; }
        __syncthreads();
        float mean = tot * (1.f / 512.f);
        float var  = totq * (1.f / 512.f) - mean * mean;
        float x1v = (s - mean) * rsqrtf(var + 1e-5f) * gpv + bpv;

        float sv2 = x1v, sq2 = x1v * x1v;
        #pragma unroll
        for (int o = 32; o > 0; o >>= 1) { sv2 += __shfl_down(sv2, o); sq2 += __shfl_down(sq2, o); }
        if ((tid & 63) == 0) { red[0][tid >> 6] = sv2; red[1][tid >> 6] = sq2; }
        __syncthreads();
        float tot2 = 0.f, totq2 = 0.f;
        #pragma unroll
        for (int i = 0; i < 8; ++i) { tot2 += red[0][i]; totq2 += red[1][i]; }
        __syncthreads();
        float m2 = tot2 * (1.f / 512.f);
        float v2 = totq2 * (1.f / 512.f) - m2 * m2;

        size_t row = (size_t)(b * N_ + h * HH_ + w);
        x1[row * D_ + d] = x1v;
        if (tid == 0) {
            stats[row * 2 + 0] = m2;
            stats[row * 2 + 1] = rsqrtf(v2 + 1e-5f);
        }
    }
}

// ---------------------------------------------------------------------------
// K2: merged q+k f32 GEMM: out = xn @ qkvw[0..1024)^T + b.  128x128 tile,
// 8x8/thread (cols strided tn+16j -> conflict-free b-reads), kslice 32.
// Per-output FMA order = kk ascending (identical to old kernel).
// LDS 33.8 KB.  grid (8, 288), 256 thr.
// ---------------------------------------------------------------------------
__global__ __launch_bounds__(256)
void gemm_f32_qk(const float* __restrict__ X1, const float* __restrict__ stats,
                 const float* __restrict__ g1, const float* __restrict__ b1,
                 const float* __restrict__ qkvw, const float* __restrict__ qkvb,
                 float* __restrict__ qb, float* __restrict__ kb)
{
    __shared__ float xnS[128][33];
    __shared__ float wS[128][33];
    const int tid = threadIdx.x;
    const int n0 = blockIdx.x * 128;
    const int m0 = blockIdx.y * 128;
    const int tm = tid >> 4, tn = tid & 15;

    float acc[8][8];
    #pragma unroll
    for (int i = 0; i < 8; ++i)
        #pragma unroll
        for (int j = 0; j < 8; ++j) acc[i][j] = 0.f;

    for (int k0 = 0; k0 < 512; k0 += 32) {
        #pragma unroll
        for (int e = 0; e < 16; ++e) {
            int i = tid + 256 * e;
            int row = i >> 5, kk = i & 31;
            float xv = X1[(size_t)(m0 + row) * 512 + k0 + kk];
            float mean = stats[(m0 + row) * 2], rs = stats[(m0 + row) * 2 + 1];
            xnS[row][kk] = (xv - mean) * rs * g1[k0 + kk] + b1[k0 + kk];
            wS[row][kk] = qkvw[(size_t)(n0 + row) * 512 + k0 + kk];
        }
        __syncthreads();
        for (int kk = 0; kk < 32; ++kk) {
            float a_[8], b_[8];
            #pragma unroll
            for (int i = 0; i < 8; ++i) a_[i] = xnS[tm * 8 + i][kk];
            #pragma unroll
            for (int j = 0; j < 8; ++j) b_[j] = wS[tn + 16 * j][kk];
            #pragma unroll
            for (int i = 0; i < 8; ++i)
                #pragma unroll
                for (int j = 0; j < 8; ++j) acc[i][j] += a_[i] * b_[j];
        }
        __syncthreads();
    }
    #pragma unroll
    for (int i = 0; i < 8; ++i) {
        #pragma unroll
        for (int j = 0; j < 8; ++j) {
            int gm = m0 + tm * 8 + i;
            int gc = n0 + tn + 16 * j;
            int b = gm / N_, n = gm - b * N_;
            float v = acc[i][j] + qkvb[gc];
            if (gc < 512) {
                qb[(((size_t)b * NH_ + (gc >> 6)) * N_ + n) * HD_ + (gc & 63)] = v;
            } else {
                kb[(((size_t)b * NH_ + ((gc >> 6) - 8)) * N_ + n) * HD_ + (gc & 63)] = v;
            }
        }
    }
}

// ---------------------------------------------------------------------------
// K3: extract landmarks from q/k buffers.  grid 32.
// ---------------------------------------------------------------------------
__global__ __launch_bounds__(256)
void extract_lm(const float* __restrict__ q, const float* __restrict__ k,
                float* __restrict__ qlf, float* __restrict__ klf,
                double* __restrict__ ql64, double* __restrict__ kl64)
{
    const int bh = blockIdx.x, tid = threadIdx.x;
    const int b = bh >> 3, h = bh & 7;
    for (int i = tid; i < 4096; i += 256) {
        int l = i >> 6, d = i & 63;
        size_t src = (((size_t)b * NH_ + h) * N_ + lm_idx(l)) * HD_ + d;
        float qv = q[src], kv = k[src];
        size_t dst = (size_t)bh * 4096 + i;
        qlf[dst] = qv; klf[dst] = kv;
        ql64[dst] = (double)qv; kl64[dst] = (double)kv;
    }
}

// ---------------------------------------------------------------------------
// K4: k2 = softmax f64; TRUNCATED PINV via Jacobi eigensolver of A^T A.
// rcond = 10*64*eps_f32 = 7.62939453125e-5 (jax pinv default).
// r16 hybrid (parallel params tid<32, wave-per-pair ILP-batched rotations,
// 3 barriers/round).  SWEEPS=8 (off-norm ~1e-16 by sweep 6; converged to
// f64 precision, output unchanged at bf16 granularity).  LDS ~101.5 KB.
// ---------------------------------------------------------------------------
__global__ __launch_bounds__(256)
void k2pinv_kernel(const double* __restrict__ ql64, const double* __restrict__ kl64,
                   double* __restrict__ k2inv)
{
    const int bh = blockIdx.x;
    const int tid = threadIdx.x;
    const int lane = tid & 63, wv = tid >> 6;
    __shared__ double A[64][65];
    __shared__ double G[64][65];
    __shared__ double V[64][65];
    __shared__ double cS[32], sS[32], wS[64];
    __shared__ int pS[32], qS[32];
    __shared__ double lmaxS;

    for (int i = tid; i < 4096; i += 256) {
        int l = i >> 6, m = i & 63;
        const double* qp = ql64 + (size_t)bh * 4096 + l * 64;
        const double* kp = kl64 + (size_t)bh * 4096 + m * 64;
        double s = 0.0;
        for (int d = 0; d < 64; ++d) s += qp[d] * kp[d];
        A[l][m] = s * 0.125;
    }
    __syncthreads();
    if (tid < 64) {
        double mx = -1e300;
        for (int j = 0; j < 64; ++j) mx = fmax(mx, A[tid][j]);
        double sm = 0.0;
        for (int j = 0; j < 64; ++j) { double e = exp(A[tid][j] - mx); A[tid][j] = e; sm += e; }
        double inv = 1.0 / sm;
        for (int j = 0; j < 64; ++j) A[tid][j] *= inv;
        A[tid][tid] += 1e-6;
    }
    __syncthreads();
    for (int e = tid; e < 4096; e += 256) {
        int i = e >> 6, j = e & 63;
        double s = 0.0;
        for (int l = 0; l < 64; ++l) s += A[l][i] * A[l][j];
        G[i][j] = s;
        V[i][j] = (i == j) ? 1.0 : 0.0;
    }
    __syncthreads();
    for (int sweep = 0; sweep < 8; ++sweep) {
        for (int r = 0; r < 63; ++r) {
            // parallel param computation: one pair per thread (tid<32)
            if (tid < 32) {
                int p, q;
                if (tid == 0) { p = 63; q = r; }
                else { p = (r + tid) % 63; q = (r - tid + 63) % 63; }
                double app = G[p][p], aqq = G[q][q], apq = G[p][q];
                double c = 1.0, s = 0.0;
                if (fabs(apq) > 1e-200) {
                    double tau = (aqq - app) / (2.0 * apq);
                    double tt = ((tau >= 0.0) ? 1.0 : -1.0) / (fabs(tau) + sqrt(1.0 + tau * tau));
                    c = 1.0 / sqrt(1.0 + tt * tt);
                    s = tt * c;
                }
                pS[tid] = p; qS[tid] = q; cS[tid] = c; sS[tid] = s;
            }
            __syncthreads();
            // fetch this wave's 8 pair params (broadcast LDS reads)
            int pA[8], qA[8];
            double cA[8], sA[8];
            #pragma unroll
            for (int t = 0; t < 8; ++t) {
                int pr = wv * 8 + t;
                pA[t] = pS[pr]; qA[t] = qS[pr]; cA[t] = cS[pr]; sA[t] = sS[pr];
            }
            // row rotations, ILP-batched: all loads, then compute+stores
            {
                double gp[8], gq[8];
                #pragma unroll
                for (int t = 0; t < 8; ++t) { gp[t] = G[pA[t]][lane]; gq[t] = G[qA[t]][lane]; }
                #pragma unroll
                for (int t = 0; t < 8; ++t) {
                    G[pA[t]][lane] = cA[t] * gp[t] - sA[t] * gq[t];
                    G[qA[t]][lane] = sA[t] * gp[t] + cA[t] * gq[t];
                }
            }
            __syncthreads();
            // col rotations + V accumulation, ILP-batched
            {
                double gp[8], gq[8], vp[8], vq[8];
                #pragma unroll
                for (int t = 0; t < 8; ++t) { gp[t] = G[lane][pA[t]]; gq[t] = G[lane][qA[t]]; }
                #pragma unroll
                for (int t = 0; t < 8; ++t) { vp[t] = V[lane][pA[t]]; vq[t] = V[lane][qA[t]]; }
                #pragma unroll
                for (int t = 0; t < 8; ++t) {
                    G[lane][pA[t]] = cA[t] * gp[t] - sA[t] * gq[t];
                    G[lane][qA[t]] = sA[t] * gp[t] + cA[t] * gq[t];
                }
                #pragma unroll
                for (int t = 0; t < 8; ++t) {
                    V[lane][pA[t]] = cA[t] * vp[t] - sA[t] * vq[t];
                    V[lane][qA[t]] = sA[t] * vp[t] + cA[t] * vq[t];
                }
            }
            __syncthreads();
        }
    }
    if (tid == 0) {
        double lm = 0.0;
        for (int j = 0; j < 64; ++j) lm = fmax(lm, G[j][j]);
        lmaxS = lm;
    }
    __syncthreads();
    if (tid < 64) {
        const double rc = 7.62939453125e-5;
        double cut = rc * rc * lmaxS;
        double l = G[tid][tid];
        wS[tid] = (l > cut) ? (1.0 / l) : 0.0;
    }
    __syncthreads();
    for (int e = tid; e < 4096; e += 256) {
        int i = e >> 6, j = e & 63;
        double s = 0.0;
        for (int m = 0; m < 64; ++m) s += V[i][m] * wS[m] * V[j][m];
        G[i][j] = s;
    }
    __syncthreads();
    for (int e = tid; e < 4096; e += 256) {
        int i = e >> 6, j = e & 63;
        double s = 0.0;
        for (int m = 0; m < 64; ++m) s += G[i][m] * A[j][m];
        k2inv[(size_t)bh * 4096 + e] = s;
    }
}

// ---------------------------------------------------------------------------
// K5: s3_U — U = P3 @ xn.  Spill-free, conflict-free LDS.  LDS 35,584 B.
// grid (NS_, 32, 4), 256 thr.
// ---------------------------------------------------------------------------
__global__ __launch_bounds__(256)
void s3_u_kernel(const float* __restrict__ qlf, const float* __restrict__ k,
                 const float* __restrict__ X1, const float* __restrict__ stats,
                 const float* __restrict__ g1, const float* __restrict__ b1,
                 float* __restrict__ Up, float* __restrict__ sp)
{
    const int s = blockIdx.x;
    const int bh = blockIdx.y;
    const int dq = blockIdx.z;
    const int tid = threadIdx.x;
    const int b = bh >> 3;
    __shared__ float qlS[64][68];
    __shared__ float kS[16][68];
    __shared__ float S[64][17];
    __shared__ float xnS[16][132];
    __shared__ float gS[128], bS[128];
    const size_t kbase = (size_t)bh * N_ * HD_;
    const int f0 = dq * 128;

    for (int i = tid; i < 4096; i += 256) qlS[i >> 6][i & 63] = qlf[(size_t)bh * 4096 + i];
    if (tid < 128) { gS[tid] = g1[f0 + tid]; bS[tid] = b1[f0 + tid]; }

    const int lp = tid >> 3;
    const int fq = tid & 7;
    f32x4 acc0[4], acc1[4];
    #pragma unroll
    for (int j = 0; j < 4; ++j) { acc0[j] = (f32x4){0,0,0,0}; acc1[j] = (f32x4){0,0,0,0}; }
    float sacc0 = 0.f, sacc1 = 0.f;

    const int nchunks = (N_ / NS_) / 16;
    for (int c = 0; c < nchunks; ++c) {
        const int n0 = s * (N_ / NS_) + c * 16;
        __syncthreads();
        {
            int i = tid * 4;
            int n = i >> 6, d = i & 63;
            float4 v = *(const float4*)(k + kbase + (size_t)(n0 + n) * HD_ + d);
            kS[n][d + 0] = v.x; kS[n][d + 1] = v.y; kS[n][d + 2] = v.z; kS[n][d + 3] = v.w;
        }
        {
            int i = tid * 8;
            int r = i >> 7, fl = i & 127;
            int gm = b * N_ + n0 + r;
            float mean = stats[gm * 2], rs = stats[gm * 2 + 1];
            const float* xp = X1 + (size_t)gm * 512 + f0 + fl;
            float4 v0 = *(const float4*)(xp);
            float4 v1 = *(const float4*)(xp + 4);
            float xv[8] = {v0.x, v0.y, v0.z, v0.w, v1.x, v1.y, v1.z, v1.w};
            #pragma unroll
            for (int e = 0; e < 8; ++e) {
                int f = fl + e;
                float val = (xv[e] - mean) * rs * gS[f] + bS[f];
                int g = f >> 2;
                int slot = ((g & 3) << 3) | (g >> 2);
                xnS[r][slot * 4 + (f & 3)] = val;
            }
        }
        __syncthreads();
        {
            const int n = tid & 15;
            const int l0 = (tid >> 4) << 2;
            const f32x4* kr4 = (const f32x4*)&kS[n][0];
            const f32x4* q0 = (const f32x4*)&qlS[l0 + 0][0];
            const f32x4* q1 = (const f32x4*)&qlS[l0 + 1][0];
            const f32x4* q2 = (const f32x4*)&qlS[l0 + 2][0];
            const f32x4* q3 = (const f32x4*)&qlS[l0 + 3][0];
            float s0 = 0.f, s1 = 0.f, s2 = 0.f, s3 = 0.f;
            #pragma unroll
            for (int d4 = 0; d4 < 16; ++d4) {
                f32x4 kv = kr4[d4];
                f32x4 a0 = q0[d4], a1 = q1[d4], a2 = q2[d4], a3 = q3[d4];
                s0 += a0.x * kv.x + a0.y * kv.y + a0.z * kv.z + a0.w * kv.w;
                s1 += a1.x * kv.x + a1.y * kv.y + a1.z * kv.z + a1.w * kv.w;
                s2 += a2.x * kv.x + a2.y * kv.y + a2.z * kv.z + a2.w * kv.w;
                s3 += a3.x * kv.x + a3.y * kv.y + a3.z * kv.z + a3.w * kv.w;
            }
            S[l0 + 0][n] = expf(s0 * SCALE_);
            S[l0 + 1][n] = expf(s1 * SCALE_);
            S[l0 + 2][n] = expf(s2 * SCALE_);
            S[l0 + 3][n] = expf(s3 * SCALE_);
        }
        __syncthreads();
        for (int n = 0; n < 16; ++n) {
            float p0 = S[2 * lp + 0][n];
            float p1 = S[2 * lp + 1][n];
            const f32x4* xr = (const f32x4*)&xnS[n][0];
            #pragma unroll
            for (int j = 0; j < 4; ++j) {
                f32x4 xv = xr[fq + 8 * j];
                acc0[j].x += p0 * xv.x; acc0[j].y += p0 * xv.y;
                acc0[j].z += p0 * xv.z; acc0[j].w += p0 * xv.w;
                acc1[j].x += p1 * xv.x; acc1[j].y += p1 * xv.y;
                acc1[j].z += p1 * xv.z; acc1[j].w += p1 * xv.w;
            }
            if (dq == 0 && fq == 0) { sacc0 += p0; sacc1 += p1; }
        }
    }
    {
        size_t ubase = (((size_t)bh * NS_ + s) * 64) * 512;
        float4* u0 = (float4*)(Up + ubase + (size_t)(2 * lp + 0) * 512 + f0 + fq * 16);
        float4* u1 = (float4*)(Up + ubase + (size_t)(2 * lp + 1) * 512 + f0 + fq * 16);
        #pragma unroll
        for (int j = 0; j < 4; ++j) {
            u0[j] = (float4){acc0[j].x, acc0[j].y, acc0[j].z, acc0[j].w};
            u1[j] = (float4){acc1[j].x, acc1[j].y, acc1[j].z, acc1[j].w};
        }
    }
    if (dq == 0 && fq == 0) {
        sp[((size_t)bh * NS_ + s) * 64 + 2 * lp + 0] = sacc0;
        sp[((size_t)bh * NS_ + s) * 64 + 2 * lp + 1] = sacc1;
    }
}

// ---------------------------------------------------------------------------
// K6a: Un = (sum_s Up) / denom.  grid 32.
// ---------------------------------------------------------------------------
__global__ __launch_bounds__(256)
void combine_u_kernel(const float* __restrict__ Up, const float* __restrict__ sp,
                      float* __restrict__ Un)
{
    const int bh = blockIdx.x, tid = threadIdx.x;
    __shared__ float dro[64];
    if (tid < 64) {
        float d = 0.f;
        for (int s = 0; s < NS_; ++s) d += sp[((size_t)bh * NS_ + s) * 64 + tid];
        dro[tid] = d;
    }
    __syncthreads();
    for (int i = tid; i < 64 * 512; i += 256) {
        int l = i >> 9;
        float a = 0.f;
        for (int s = 0; s < NS_; ++s) a += Up[(((size_t)bh * NS_ + s) * 64) * 512 + i];
        Un[(size_t)bh * 64 * 512 + i] = a / dro[l];
    }
}

// ---------------------------------------------------------------------------
// K6b: Tn = Un @ Wv_head^T + bv.  grid 32.
// ---------------------------------------------------------------------------
__global__ __launch_bounds__(256)
void tn_kernel(const float* __restrict__ Un, const float* __restrict__ qkvw,
               const float* __restrict__ qkvb, float* __restrict__ Tn)
{
    const int bh = blockIdx.x, tid = threadIdx.x;
    const int h = bh & 7;
    const int l = tid >> 2, d0 = (tid & 3) * 16;
    const float* un = Un + (size_t)bh * 64 * 512 + l * 512;
    for (int j = 0; j < 16; ++j) {
        int d = d0 + j;
        const float* wv = qkvw + (size_t)(1024 + h * 64 + d) * 512;
        float t = 0.f;
        for (int f = 0; f < 512; ++f) t += un[f] * wv[f];
        Tn[(size_t)bh * 4096 + l * 64 + d] = t + qkvb[1024 + h * 64 + d];
    }
}

// ---------------------------------------------------------------------------
// K6c: W2 = k2pinv @ Tn.  grid 32.  LDS 16 KB.
// ---------------------------------------------------------------------------
__global__ __launch_bounds__(256)
void combine_b_kernel(const float* __restrict__ Tn, const double* __restrict__ k2inv,
                      float* __restrict__ W2)
{
    const int bh = blockIdx.x, tid = threadIdx.x;
    __shared__ float Tl[64][64];
    for (int i = tid; i < 4096; i += 256) Tl[i >> 6][i & 63] = Tn[(size_t)bh * 4096 + i];
    __syncthreads();
    const int l = tid >> 2, d0 = (tid & 3) * 16;
    float o[16];
    #pragma unroll
    for (int j = 0; j < 16; ++j) o[j] = 0.f;
    const double* kr = k2inv + (size_t)bh * 4096 + l * 64;
    for (int j2 = 0; j2 < 64; ++j2) {
        float a = (float)kr[j2];
        const float* tr = &Tl[j2][d0];
        #pragma unroll
        for (int j = 0; j < 16; ++j) o[j] += a * tr[j];
    }
    float* wp = W2 + (size_t)bh * 4096 + l * 64 + d0;
    #pragma unroll
    for (int j = 0; j < 16; ++j) wp[j] = o[j];
}

// ---------------------------------------------------------------------------
// K7: att = softmax(q·kl^T/8) @ W2 -> bf16 hi/lo.  LDS 32768 B.
// ---------------------------------------------------------------------------
__global__ __launch_bounds__(256)
void k1pv_kernel(const float* __restrict__ q, const float* __restrict__ klf,
                 const float* __restrict__ W2,
                 unsigned short* __restrict__ atth, unsigned short* __restrict__ attl)
{
    const int nc = blockIdx.x;
    const int bh = blockIdx.y;
    const int tid = threadIdx.x;
    __shared__ float klS[64][64];
    __shared__ float W2S[64][64];
    const size_t base = (size_t)bh * N_ * HD_;
    for (int i = tid; i < 4096; i += 256) {
        klS[i >> 6][i & 63] = klf[(size_t)bh * 4096 + i];
        W2S[i >> 6][i & 63] = W2[(size_t)bh * 4096 + i];
    }
    __syncthreads();
    const int n = nc * 256 + tid;
    float qf[64];
    const float4* qr = (const float4*)(q + base + (size_t)n * HD_);
    #pragma unroll
    for (int j = 0; j < 16; ++j) { float4 u = qr[j]; qf[j*4]=u.x; qf[j*4+1]=u.y; qf[j*4+2]=u.z; qf[j*4+3]=u.w; }
    float s[64];
    #pragma unroll
    for (int l = 0; l < 64; ++l) {
        const f32x4* kl4 = (const f32x4*)&klS[l][0];
        float t = 0.f;
        #pragma unroll
        for (int d4 = 0; d4 < 16; ++d4) {
            f32x4 w4 = kl4[d4];
            t += w4.x * qf[d4*4] + w4.y * qf[d4*4+1] + w4.z * qf[d4*4+2] + w4.w * qf[d4*4+3];
        }
        s[l] = t * SCALE_;
    }
    float mx = -1e30f;
    #pragma unroll
    for (int l = 0; l < 64; ++l) mx = fmaxf(mx, s[l]);
    float sum = 0.f;
    #pragma unroll
    for (int l = 0; l < 64; ++l) { s[l] = expf(s[l] - mx); sum += s[l]; }
    float inv = 1.f / sum;
    float acc[64];
    #pragma unroll
    for (int d2 = 0; d2 < 64; ++d2) acc[d2] = 0.f;
    #pragma unroll
    for (int l = 0; l < 64; ++l) {
        float p = s[l] * inv;
        const f32x4* w4p = (const f32x4*)&W2S[l][0];
        #pragma unroll
        for (int d4 = 0; d4 < 16; ++d4) {
            f32x4 w4 = w4p[d4];
            acc[d4*4+0] += p * w4.x; acc[d4*4+1] += p * w4.y;
            acc[d4*4+2] += p * w4.z; acc[d4*4+3] += p * w4.w;
        }
    }
    unsigned short* oh = atth + base + (size_t)n * HD_;
    unsigned short* ol = attl + base + (size_t)n * HD_;
    #pragma unroll
    for (int j = 0; j < 8; ++j) {
        float hv[8], lv[8];
        #pragma unroll
        for (int e = 0; e < 8; ++e) {
            float a = acc[j * 8 + e];
            unsigned short hb = f2bf(a);
            hv[e] = bf2f(hb);
            lv[e] = a - hv[e];
        }
        uint4 uh, ul;
        uh.x = pk2(hv[0], hv[1]); uh.y = pk2(hv[2], hv[3]);
        uh.z = pk2(hv[4], hv[5]); uh.w = pk2(hv[6], hv[7]);
        ul.x = pk2(lv[0], lv[1]); ul.y = pk2(lv[2], lv[3]);
        ul.z = pk2(lv[4], lv[5]); ul.w = pk2(lv[6], lv[7]);
        ((uint4*)oh)[j] = uh;
        ((uint4*)ol)[j] = ul;
    }
}

// ---------------------------------------------------------------------------
// K8: proj GEMM — split-precision MFMA (3-pass bf16 hi/lo), 128x64, BK=32.
// ---------------------------------------------------------------------------
__global__ __launch_bounds__(256)
void gemm_proj(const unsigned short* __restrict__ Aa, const unsigned short* __restrict__ Ab,
               const unsigned short* __restrict__ Wh, const unsigned short* __restrict__ Wl,
               const float* __restrict__ bias, float* __restrict__ fo0)
{
    __shared__ __align__(16) char AsH[8192];
    __shared__ __align__(16) char AsL[8192];
    __shared__ __align__(16) char BsH[4096];
    __shared__ __align__(16) char BsL[4096];
    const int tid = threadIdx.x;
    const int wv = tid >> 6, lane = tid & 63;
    const int wm = wv >> 1, wn = wv & 1;
    const int n0 = blockIdx.x * 64;
    const int m0 = blockIdx.y * 128;

    f32x4 acc[4][2];
    #pragma unroll
    for (int i = 0; i < 4; ++i)
        #pragma unroll
        for (int j = 0; j < 2; ++j) acc[i][j] = (f32x4){0.f, 0.f, 0.f, 0.f};

    for (int k0 = 0; k0 < 512; k0 += 32) {
        {
            int row = wv * 16 + (lane >> 2);
            int sl = lane & 3;
            int kk = k0 + ((sl ^ (row & 3)) << 3);
            const unsigned short* s0 = Wh + (size_t)(n0 + row) * 512 + kk;
            __builtin_amdgcn_global_load_lds((const u32g*)s0, (u32l*)(BsH + wv * 1024), 16, 0, 0);
            const unsigned short* s1 = Wl + (size_t)(n0 + row) * 512 + kk;
            __builtin_amdgcn_global_load_lds((const u32g*)s1, (u32l*)(BsL + wv * 1024), 16, 0, 0);
        }
        #pragma unroll
        for (int t = 0; t < 2; ++t) {
            int row = wv * 32 + t * 16 + (lane >> 2);
            int sl = lane & 3;
            int kk = k0 + ((sl ^ (row & 3)) << 3);
            int m = m0 + row;
            int b = m / N_; int n = m - b * N_; int hh = kk >> 6; int dd = kk & 63;
            size_t adr = (((size_t)b * NH_ + hh) * N_ + n) * HD_ + dd;
            __builtin_amdgcn_global_load_lds((const u32g*)(Aa + adr),
                                             (u32l*)(AsH + wv * 2048 + t * 1024), 16, 0, 0);
            __builtin_amdgcn_global_load_lds((const u32g*)(Ab + adr),
                                             (u32l*)(AsL + wv * 2048 + t * 1024), 16, 0, 0);
        }
        __syncthreads();
        bf16x8 afh[4], afl[4], bfh[2], bfl[2];
        #pragma unroll
        for (int mf = 0; mf < 4; ++mf) {
            int r = wm * 64 + mf * 16 + (lane & 15);
            int ps = (lane >> 4) ^ (r & 3);
            afh[mf] = *(const bf16x8*)(AsH + r * 64 + ps * 16);
            afl[mf] = *(const bf16x8*)(AsL + r * 64 + ps * 16);
        }
        #pragma unroll
        for (int nf = 0; nf < 2; ++nf) {
            int r = wn * 32 + nf * 16 + (lane & 15);
            int ps = (lane >> 4) ^ (r & 3);
            bfh[nf] = *(const bf16x8*)(BsH + r * 64 + ps * 16);
            bfl[nf] = *(const bf16x8*)(BsL + r * 64 + ps * 16);
        }
        #pragma unroll
        for (int mf = 0; mf < 4; ++mf)
            #pragma unroll
            for (int nf = 0; nf < 2; ++nf) {
                acc[mf][nf] = __builtin_amdgcn_mfma_f32_16x16x32_bf16(afh[mf], bfh[nf], acc[mf][nf], 0, 0, 0);
                acc[mf][nf] = __builtin_amdgcn_mfma_f32_16x16x32_bf16(afh[mf], bfl[nf], acc[mf][nf], 0, 0, 0);
                acc[mf][nf] = __builtin_amdgcn_mfma_f32_16x16x32_bf16(afl[mf], bfh[nf], acc[mf][nf], 0, 0, 0);
            }
        __syncthreads();
    }

    const int lc = lane & 15, lr4 = (lane >> 4) * 4;
    float bcol[2];
    #pragma unroll
    for (int nf = 0; nf < 2; ++nf)
        bcol[nf] = bias[n0 + wn * 32 + nf * 16 + lc];

    #pragma unroll
    for (int mf = 0; mf < 4; ++mf) {
        #pragma unroll
        for (int nf = 0; nf < 2; ++nf) {
            #pragma unroll
            for (int i = 0; i < 4; ++i) {
                int gm = m0 + wm * 64 + mf * 16 + lr4 + i;
                int gn = n0 + wn * 32 + nf * 16 + lc;
                fo0[(size_t)gm * 512 + gn] = acc[mf][nf][i] + bcol[nf];
            }
        }
    }
}

// ---------------------------------------------------------------------------
// K9: resid — x2 = x1 + pjo (in-place on pjo); xn2 = bf16(LN(x2, norm2)).
// ---------------------------------------------------------------------------
__global__ __launch_bounds__(256)
void resid_ln_kernel(const float* __restrict__ x1, float* __restrict__ pjo_x2,
                     const float* __restrict__ g, const float* __restrict__ bb,
                     unsigned short* __restrict__ xn2h)
{
    const int row = blockIdx.x, tid = threadIdx.x;
    const size_t base = (size_t)row * D_;
    float a0 = x1[base + tid]       + pjo_x2[base + tid];
    float a1 = x1[base + 256 + tid] + pjo_x2[base + 256 + tid];
    __shared__ float red[2][4];
    float sv = a0 + a1, sq = a0 * a0 + a1 * a1;
    #pragma unroll
    for (int o = 32; o > 0; o >>= 1) { sv += __shfl_down(sv, o); sq += __shfl_down(sq, o); }
    if ((tid & 63) == 0) { red[0][tid >> 6] = sv; red[1][tid >> 6] = sq; }
    __syncthreads();
    float tot = 0.f, totq = 0.f;
    #pragma unroll
    for (int i = 0; i < 4; ++i) { tot += red[0][i]; totq += red[1][i]; }
    float mean = tot * (1.f / 512.f);
    float var  = totq * (1.f / 512.f) - mean * mean;
    float rs = rsqrtf(var + 1e-5f);
    float o0 = (a0 - mean) * rs * g[tid]       + bb[tid];
    float o1 = (a1 - mean) * rs * g[256 + tid] + bb[256 + tid];
    pjo_x2[base + tid] = a0;
    pjo_x2[base + 256 + tid] = a1;
    xn2h[base + tid] = f2bf(o0);
    xn2h[base + 256 + tid] = f2bf(o1);
}

// ---------------------------------------------------------------------------
// K10: plain bf16 MFMA GEMM (MLP), 128x128 tile, BK=64.  LDS 32768 B.
// ---------------------------------------------------------------------------
#define E_GELU 0
#define E_ACC 1
#define E_FIN 2

template<int KLEN, int ALDA, int WLDA, int EPI, int OSTR>
__global__ __launch_bounds__(256)
void gemm_plain(const unsigned short* __restrict__ Aa,
                const unsigned short* __restrict__ Wh,
                int wrow0, int wcol0,
                const float* __restrict__ bias, int bias0,
                unsigned short* __restrict__ bo0, float* __restrict__ fo0,
                const unsigned short* __restrict__ accb, const float* __restrict__ resid)
{
    __shared__ __align__(16) char As[16384];
    __shared__ __align__(16) char Bs[16384];
    const int tid = threadIdx.x;
    const int wv = tid >> 6, lane = tid & 63;
    const int wm = wv >> 1, wn = wv & 1;
    const int n0 = blockIdx.x * 128;
    const int m0 = blockIdx.y * 128;
    const int rl = lane >> 3, sl = lane & 7;

    f32x4 acc[4][4];
    #pragma unroll
    for (int i = 0; i < 4; ++i)
        #pragma unroll
        for (int j = 0; j < 4; ++j) acc[i][j] = (f32x4){0.f, 0.f, 0.f, 0.f};

    for (int k0 = 0; k0 < KLEN; k0 += 64) {
        #pragma unroll
        for (int t = 0; t < 4; ++t) {
            int row = wv * 32 + t * 8 + rl;
            int slot = sl ^ (row & 7);
            const unsigned short* srcW = Wh + (size_t)(wrow0 + n0 + row) * WLDA + wcol0 + k0 + slot * 8;
            __builtin_amdgcn_global_load_lds((const u32g*)srcW, (u32l*)(Bs + wv * 4096 + t * 1024), 16, 0, 0);
            const unsigned short* srcA = Aa + (size_t)(m0 + row) * ALDA + k0 + slot * 8;
            __builtin_amdgcn_global_load_lds((const u32g*)srcA, (u32l*)(As + wv * 4096 + t * 1024), 16, 0, 0);
        }
        __syncthreads();
        #pragma unroll
        for (int ks = 0; ks < 2; ++ks) {
            bf16x8 af[4], bfr[4];
            #pragma unroll
            for (int mf = 0; mf < 4; ++mf) {
                int r = wm * 64 + mf * 16 + (lane & 15);
                int ps = (ks * 4 + (lane >> 4)) ^ (r & 7);
                af[mf] = *(const bf16x8*)(As + r * 128 + ps * 16);
            }
            #pragma unroll
            for (int nf = 0; nf < 4; ++nf) {
                int r = wn * 64 + nf * 16 + (lane & 15);
                int ps = (ks * 4 + (lane >> 4)) ^ (r & 7);
                bfr[nf] = *(const bf16x8*)(Bs + r * 128 + ps * 16);
            }
            #pragma unroll
            for (int mf = 0; mf < 4; ++mf)
                #pragma unroll
                for (int nf = 0; nf < 4; ++nf)
                    acc[mf][nf] = __builtin_amdgcn_mfma_f32_16x16x32_bf16(af[mf], bfr[nf], acc[mf][nf], 0, 0, 0);
        }
        __syncthreads();
    }

    const int lc = lane & 15, lr4 = (lane >> 4) * 4;
    float bcol[4];
    #pragma unroll
    for (int nf = 0; nf < 4; ++nf)
        bcol[nf] = bias ? bias[bias0 + n0 + wn * 64 + nf * 16 + lc] : 0.f;

    #pragma unroll
    for (int mf = 0; mf < 4; ++mf) {
        #pragma unroll
        for (int nf = 0; nf < 4; ++nf) {
            #pragma unroll
            for (int i = 0; i < 4; ++i) {
                int gm = m0 + wm * 64 + mf * 16 + lr4 + i;
                int gn = n0 + wn * 64 + nf * 16 + lc;
                float val = acc[mf][nf][i] + bcol[nf];
                if (EPI == E_GELU) {
                    float g = 0.5f * val * (1.f + erff(val * 0.70710678118f));
                    bo0[(size_t)gm * OSTR + gn] = f2bf(g);
                } else if (EPI == E_ACC) {
                    bo0[(size_t)gm * OSTR + gn] = f2bf(val);
                } else {
                    fo0[(size_t)gm * 512 + gn] = val + bf2f(accb[(size_t)gm * 512 + gn])
                                               + resid[(size_t)gm * 512 + gn];
                }
            }
        }
    }
}

// ---------------------------------------------------------------------------
extern "C" void kernel_launch(void* const* d_in, const int* in_sizes, int n_in,
                              void* d_out, int out_size, void* d_ws, size_t ws_size,
                              hipStream_t stream) {
    const float* x    = (const float*)d_in[0];
    const float* c1w  = (const float*)d_in[1];
    const float* c1b  = (const float*)d_in[2];
    const float* c2w  = (const float*)d_in[3];
    const float* c2b  = (const float*)d_in[4];
    const float* c3w  = (const float*)d_in[5];
    const float* c3b  = (const float*)d_in[6];
    const float* pg   = (const float*)d_in[7];
    const float* pb   = (const float*)d_in[8];
    const float* n1g  = (const float*)d_in[9];
    const float* n1b  = (const float*)d_in[10];
    const float* n2g  = (const float*)d_in[11];
    const float* n2b  = (const float*)d_in[12];
    const float* qkvw = (const float*)d_in[13];
    const float* qkvb = (const float*)d_in[14];
    const float* pjw  = (const float*)d_in[15];
    const float* pjb  = (const float*)d_in[16];
    const float* w1   = (const float*)d_in[17];
    const float* b1   = (const float*)d_in[18];
    const float* w2m  = (const float*)d_in[19];
    const float* b2m  = (const float*)d_in[20];

    char* ws = (char*)d_ws;
    char* RA = ws;
    char* RB = ws + 75497472;
    char* RC = ws + 150994944;
    char* R3 = ws + 226492416;
    unsigned short* pwh  = (unsigned short*)(R3 + 0);
    unsigned short* pwl  = (unsigned short*)(R3 + 524288);
    unsigned short* w1b  = (unsigned short*)(R3 + 1048576);
    unsigned short* w2b  = (unsigned short*)(R3 + 3145728);
    float*  stats = (float*)(R3 + 5242880);
    float*  qlf   = (float*)(R3 + 5537792);
    float*  klf   = (float*)(R3 + 6062080);
    double* ql64  = (double*)(R3 + 6586368);
    double* kl64  = (double*)(R3 + 7634944);
    double* k2i   = (double*)(R3 + 8683520);
    float*  W2    = (float*)(R3 + 9732096);
    float*  Tn    = (float*)(R3 + 10256384);
    float*  sp    = (float*)(R3 + 10780672);
    float*  Up    = (float*)(R3 + 10813440);
    float*  Un    = (float*)(R3 + 27590656);

    float* x1 = (float*)RA;
    float* kb = (float*)RB;
    float* qb = (float*)RC;
    unsigned short* atth = (unsigned short*)RB;
    unsigned short* attl = (unsigned short*)(RB + 37748736);
    float* pjo = (float*)RC;
    unsigned short* xn2  = (unsigned short*)RB;
    unsigned short* accb = (unsigned short*)(RB + 37748736);
    unsigned short* hbuf = (unsigned short*)RA;

    prep_weights<<<1024, 256, 0, stream>>>(pjw, w1, w2m, pwh, pwl, w1b, w2b);
    ppeg_ln_kernel<<<B_ * HH_, 512, 0, stream>>>(x, c1w, c1b, c2w, c2b, c3w, c3b,
                                                 pg, pb, x1, stats);
    gemm_f32_qk<<<dim3(8, 288), 256, 0, stream>>>(x1, stats, n1g, n1b, qkvw, qkvb, qb, kb);
    extract_lm<<<32, 256, 0, stream>>>(qb, kb, qlf, klf, ql64, kl64);
    k2pinv_kernel<<<32, 256, 0, stream>>>(ql64, kl64, k2i);
    s3_u_kernel<<<dim3(NS_, 32, 4), 256, 0, stream>>>(qlf, kb, x1, stats, n1g, n1b, Up, sp);
    combine_u_kernel<<<32, 256, 0, stream>>>(Up, sp, Un);
    tn_kernel<<<32, 256, 0, stream>>>(Un, qkvw, qkvb, Tn);
    combine_b_kernel<<<32, 256, 0, stream>>>(Tn, k2i, W2);
    k1pv_kernel<<<dim3(36, 32), 256, 0, stream>>>(qb, klf, W2, atth, attl);
    gemm_proj<<<dim3(8, 288), 256, 0, stream>>>(atth, attl, pwh, pwl, pjb, pjo);
    resid_ln_kernel<<<MT_, 256, 0, stream>>>(x1, pjo, n2g, n2b, xn2);
    gemm_plain<512, 512, 512, E_GELU, 1024><<<dim3(8, 288), 256, 0, stream>>>(
        xn2, w1b, 0, 0, b1, 0, hbuf, nullptr, nullptr, nullptr);
    gemm_plain<1024, 1024, 2048, E_ACC, 512><<<dim3(4, 288), 256, 0, stream>>>(
        hbuf, w2b, 0, 0, nullptr, 0, accb, nullptr, nullptr, nullptr);
    gemm_plain<512, 512, 512, E_GELU, 1024><<<dim3(8, 288), 256, 0, stream>>>(
        xn2, w1b, 1024, 0, b1, 1024, hbuf, nullptr, nullptr, nullptr);
    gemm_plain<1024, 1024, 2048, E_FIN, 512><<<dim3(4, 288), 256, 0, stream>>>(
        hbuf, w2b, 0, 1024, b2m, 0, nullptr, (float*)d_out, accb, pjo);
}

// Round 19
// 3845.212 us; speedup vs baseline: 1.3337x; 1.1829x over previous
//
#include <hip/hip_runtime.h>

typedef unsigned int u32;
typedef short bf16x8 __attribute__((ext_vector_type(8)));
typedef float f32x4 __attribute__((ext_vector_type(4)));
typedef u32 __attribute__((address_space(1))) u32g;
typedef u32 __attribute__((address_space(3))) u32l;

#define B_  4
#define N_  9216
#define D_  512
#define NH_ 8
#define HD_ 64
#define L_  64
#define HH_ 96
#define MT_ 36864
#define SCALE_ 0.125f
#define NS_ 4   /* s3 splits */

__device__ __forceinline__ float bf2f(unsigned short u) {
    union { u32 i; float f; } c; c.i = ((u32)u) << 16; return c.f;
}
__device__ __forceinline__ unsigned short f2bf(float f) {
    u32 x = __float_as_uint(f);
    return (unsigned short)((x + 0x7fffu + ((x >> 16) & 1u)) >> 16);
}
__device__ __forceinline__ int lm_idx(int l){ return (l * 9215) / 63; }
__device__ __forceinline__ u32 pk2(float a, float b){ return (u32)f2bf(a) | ((u32)f2bf(b) << 16); }

// ---------------------------------------------------------------------------
// K0: weight prep — proj_w -> bf16 hi/lo; mlp w1/w2 -> bf16.
// ---------------------------------------------------------------------------
#define PJW_N  262144
#define MLPW_N 1048576
__global__ __launch_bounds__(256)
void prep_weights(const float* __restrict__ pjw,
                  const float* __restrict__ w1, const float* __restrict__ w2,
                  unsigned short* __restrict__ pwh, unsigned short* __restrict__ pwl,
                  unsigned short* __restrict__ w1b, unsigned short* __restrict__ w2b)
{
    const int total = PJW_N + MLPW_N + MLPW_N;
    for (int i = blockIdx.x * 256 + threadIdx.x; i < total; i += gridDim.x * 256) {
        if (i < PJW_N) {
            float v = pjw[i]; unsigned short h = f2bf(v);
            pwh[i] = h; pwl[i] = f2bf(v - bf2f(h));
        } else if (i < PJW_N + MLPW_N) {
            int j = i - PJW_N;
            w1b[j] = f2bf(w1[j]);
        } else {
            int j = i - PJW_N - MLPW_N;
            w2b[j] = f2bf(w2[j]);
        }
    }
}

// ---------------------------------------------------------------------------
// K1: PPEG + residual + LN(ppeg) -> x1 (f32) + norm1 stats.
// TLP rework: grid (8 wchunks, 384 rows) — 3072 blocks; each block does 12
// w-positions with a register SLIDING WINDOW (7 loads/iter instead of 49;
// out-of-range taps load 0.0 -> exact +0.0 adds, same accumulation order).
// LDS 64 B.
// ---------------------------------------------------------------------------
__global__ __launch_bounds__(512)
void ppeg_ln_kernel(const float* __restrict__ x,
                    const float* __restrict__ c1w, const float* __restrict__ c1b,
                    const float* __restrict__ c2w, const float* __restrict__ c2b,
                    const float* __restrict__ c3w, const float* __restrict__ c3b,
                    const float* __restrict__ pg, const float* __restrict__ pb,
                    float* __restrict__ x1, float* __restrict__ stats)
{
    const int bh = blockIdx.y;
    const int b = bh / HH_;
    const int h = bh % HH_;
    const int w0 = blockIdx.x * 12;
    const int d = threadIdx.x;
    const int tid = threadIdx.x;

    float wtap[49];
    #pragma unroll
    for (int i = 0; i < 49; ++i) wtap[i] = c3w[d * 49 + i];
    #pragma unroll
    for (int ky = 0; ky < 5; ++ky)
        #pragma unroll
        for (int kx = 0; kx < 5; ++kx)
            wtap[(ky + 1) * 7 + (kx + 1)] += c2w[d * 25 + ky * 5 + kx];
    #pragma unroll
    for (int ky = 0; ky < 3; ++ky)
        #pragma unroll
        for (int kx = 0; kx < 3; ++kx)
            wtap[(ky + 2) * 7 + (kx + 2)] += c1w[d * 9 + ky * 3 + kx];

    const float bsum = c1b[d] + c2b[d] + c3b[d];
    const float gpv = pg[d], bpv = pb[d];

    __shared__ float red[2][8];

    // initial window: columns ww = w0-3 .. w0+2 into win[r][0..5]
    float win[7][7];
    #pragma unroll
    for (int r = 0; r < 7; ++r) {
        int hh = h + r - 3;
        bool hok = (hh >= 0 && hh < HH_);
        #pragma unroll
        for (int j = 0; j < 6; ++j) {
            int ww = w0 - 3 + j;
            win[r][j] = (hok && ww >= 0 && ww < HH_)
                      ? x[(size_t)(b * N_ + hh * HH_ + ww) * D_ + d] : 0.f;
        }
    }

    for (int wi = 0; wi < 12; ++wi) {
        const int w = w0 + wi;
        // load incoming column ww = w+3 into win[r][6]
        {
            int ww = w + 3;
            bool wok = (ww < HH_);
            #pragma unroll
            for (int r = 0; r < 7; ++r) {
                int hh = h + r - 3;
                win[r][6] = (wok && hh >= 0 && hh < HH_)
                          ? x[(size_t)(b * N_ + hh * HH_ + ww) * D_ + d] : 0.f;
            }
        }
        float pos = bsum;
        #pragma unroll
        for (int r = 0; r < 7; ++r)
            #pragma unroll
            for (int j = 0; j < 7; ++j)
                pos += win[r][j] * wtap[r * 7 + j];
        float xc = win[3][3];
        float s = xc + pos;

        float sv = s, sq = s * s;
        #pragma unroll
        for (int o = 32; o > 0; o >>= 1) { sv += __shfl_down(sv, o); sq += __shfl_down(sq, o); }
        if ((tid & 63) == 0) { red[0][tid >> 6] = sv; red[1][tid >> 6] = sq; }
        __syncthreads();
        float tot = 0.f, totq = 0.f;
        #pragma unroll
        for (int i = 0; i < 8; ++i) { tot += red[0][i]; totq += red[1][i]; }
        __syncthreads();
        float mean = tot * (1.f / 512.f);
        float var  = totq * (1.f / 512.f) - mean * mean;
        float x1v = (s - mean) * rsqrtf(var + 1e-5f) * gpv + bpv;

        float sv2 = x1v, sq2 = x1v * x1v;
        #pragma unroll
        for (int o = 32; o > 0; o >>= 1) { sv2 += __shfl_down(sv2, o); sq2 += __shfl_down(sq2, o); }
        if ((tid & 63) == 0) { red[0][tid >> 6] = sv2; red[1][tid >> 6] = sq2; }
        __syncthreads();
        float tot2 = 0.f, totq2 = 0.f;
        #pragma unroll
        for (int i = 0; i < 8; ++i) { tot2 += red[0][i]; totq2 += red[1][i]; }
        __syncthreads();
        float m2 = tot2 * (1.f / 512.f);
        float v2 = totq2 * (1.f / 512.f) - m2 * m2;

        size_t row = (size_t)(b * N_ + h * HH_ + w);
        x1[row * D_ + d] = x1v;
        if (tid == 0) {
            stats[row * 2 + 0] = m2;
            stats[row * 2 + 1] = rsqrtf(v2 + 1e-5f);
        }
        // shift window left
        #pragma unroll
        for (int r = 0; r < 7; ++r)
            #pragma unroll
            for (int j = 0; j < 6; ++j)
                win[r][j] = win[r][j + 1];
    }
}

// ---------------------------------------------------------------------------
// K2: merged q+k f32 GEMM: out = xn @ qkvw[0..1024)^T + b.  128x128 tile,
// 8x8/thread (cols strided tn+16j -> conflict-free b-reads), kslice 32.
// LDS 33.8 KB.  grid (8, 288), 256 thr.
// ---------------------------------------------------------------------------
__global__ __launch_bounds__(256)
void gemm_f32_qk(const float* __restrict__ X1, const float* __restrict__ stats,
                 const float* __restrict__ g1, const float* __restrict__ b1,
                 const float* __restrict__ qkvw, const float* __restrict__ qkvb,
                 float* __restrict__ qb, float* __restrict__ kb)
{
    __shared__ float xnS[128][33];
    __shared__ float wS[128][33];
    const int tid = threadIdx.x;
    const int n0 = blockIdx.x * 128;
    const int m0 = blockIdx.y * 128;
    const int tm = tid >> 4, tn = tid & 15;

    float acc[8][8];
    #pragma unroll
    for (int i = 0; i < 8; ++i)
        #pragma unroll
        for (int j = 0; j < 8; ++j) acc[i][j] = 0.f;

    for (int k0 = 0; k0 < 512; k0 += 32) {
        #pragma unroll
        for (int e = 0; e < 16; ++e) {
            int i = tid + 256 * e;
            int row = i >> 5, kk = i & 31;
            float xv = X1[(size_t)(m0 + row) * 512 + k0 + kk];
            float mean = stats[(m0 + row) * 2], rs = stats[(m0 + row) * 2 + 1];
            xnS[row][kk] = (xv - mean) * rs * g1[k0 + kk] + b1[k0 + kk];
            wS[row][kk] = qkvw[(size_t)(n0 + row) * 512 + k0 + kk];
        }
        __syncthreads();
        for (int kk = 0; kk < 32; ++kk) {
            float a_[8], b_[8];
            #pragma unroll
            for (int i = 0; i < 8; ++i) a_[i] = xnS[tm * 8 + i][kk];
            #pragma unroll
            for (int j = 0; j < 8; ++j) b_[j] = wS[tn + 16 * j][kk];
            #pragma unroll
            for (int i = 0; i < 8; ++i)
                #pragma unroll
                for (int j = 0; j < 8; ++j) acc[i][j] += a_[i] * b_[j];
        }
        __syncthreads();
    }
    #pragma unroll
    for (int i = 0; i < 8; ++i) {
        #pragma unroll
        for (int j = 0; j < 8; ++j) {
            int gm = m0 + tm * 8 + i;
            int gc = n0 + tn + 16 * j;
            int b = gm / N_, n = gm - b * N_;
            float v = acc[i][j] + qkvb[gc];
            if (gc < 512) {
                qb[(((size_t)b * NH_ + (gc >> 6)) * N_ + n) * HD_ + (gc & 63)] = v;
            } else {
                kb[(((size_t)b * NH_ + ((gc >> 6) - 8)) * N_ + n) * HD_ + (gc & 63)] = v;
            }
        }
    }
}

// ---------------------------------------------------------------------------
// K3: extract landmarks from q/k buffers.  grid 32.
// ---------------------------------------------------------------------------
__global__ __launch_bounds__(256)
void extract_lm(const float* __restrict__ q, const float* __restrict__ k,
                float* __restrict__ qlf, float* __restrict__ klf,
                double* __restrict__ ql64, double* __restrict__ kl64)
{
    const int bh = blockIdx.x, tid = threadIdx.x;
    const int b = bh >> 3, h = bh & 7;
    for (int i = tid; i < 4096; i += 256) {
        int l = i >> 6, d = i & 63;
        size_t src = (((size_t)b * NH_ + h) * N_ + lm_idx(l)) * HD_ + d;
        float qv = q[src], kv = k[src];
        size_t dst = (size_t)bh * 4096 + i;
        qlf[dst] = qv; klf[dst] = kv;
        ql64[dst] = (double)qv; kl64[dst] = (double)kv;
    }
}

// ---------------------------------------------------------------------------
// K4: k2 = softmax f64; TRUNCATED PINV via Jacobi eigensolver of A^T A.
// rcond = 10*64*eps_f32 = 7.62939453125e-5 (jax pinv default).
// r16 hybrid (parallel params tid<32, wave-per-pair ILP-batched rotations,
// 3 barriers/round).  SWEEPS=8.  LDS ~101.5 KB.
// ---------------------------------------------------------------------------
__global__ __launch_bounds__(256)
void k2pinv_kernel(const double* __restrict__ ql64, const double* __restrict__ kl64,
                   double* __restrict__ k2inv)
{
    const int bh = blockIdx.x;
    const int tid = threadIdx.x;
    const int lane = tid & 63, wv = tid >> 6;
    __shared__ double A[64][65];
    __shared__ double G[64][65];
    __shared__ double V[64][65];
    __shared__ double cS[32], sS[32], wS[64];
    __shared__ int pS[32], qS[32];
    __shared__ double lmaxS;

    for (int i = tid; i < 4096; i += 256) {
        int l = i >> 6, m = i & 63;
        const double* qp = ql64 + (size_t)bh * 4096 + l * 64;
        const double* kp = kl64 + (size_t)bh * 4096 + m * 64;
        double s = 0.0;
        for (int d = 0; d < 64; ++d) s += qp[d] * kp[d];
        A[l][m] = s * 0.125;
    }
    __syncthreads();
    if (tid < 64) {
        double mx = -1e300;
        for (int j = 0; j < 64; ++j) mx = fmax(mx, A[tid][j]);
        double sm = 0.0;
        for (int j = 0; j < 64; ++j) { double e = exp(A[tid][j] - mx); A[tid][j] = e; sm += e; }
        double inv = 1.0 / sm;
        for (int j = 0; j < 64; ++j) A[tid][j] *= inv;
        A[tid][tid] += 1e-6;
    }
    __syncthreads();
    for (int e = tid; e < 4096; e += 256) {
        int i = e >> 6, j = e & 63;
        double s = 0.0;
        for (int l = 0; l < 64; ++l) s += A[l][i] * A[l][j];
        G[i][j] = s;
        V[i][j] = (i == j) ? 1.0 : 0.0;
    }
    __syncthreads();
    for (int sweep = 0; sweep < 8; ++sweep) {
        for (int r = 0; r < 63; ++r) {
            if (tid < 32) {
                int p, q;
                if (tid == 0) { p = 63; q = r; }
                else { p = (r + tid) % 63; q = (r - tid + 63) % 63; }
                double app = G[p][p], aqq = G[q][q], apq = G[p][q];
                double c = 1.0, s = 0.0;
                if (fabs(apq) > 1e-200) {
                    double tau = (aqq - app) / (2.0 * apq);
                    double tt = ((tau >= 0.0) ? 1.0 : -1.0) / (fabs(tau) + sqrt(1.0 + tau * tau));
                    c = 1.0 / sqrt(1.0 + tt * tt);
                    s = tt * c;
                }
                pS[tid] = p; qS[tid] = q; cS[tid] = c; sS[tid] = s;
            }
            __syncthreads();
            int pA[8], qA[8];
            double cA[8], sA[8];
            #pragma unroll
            for (int t = 0; t < 8; ++t) {
                int pr = wv * 8 + t;
                pA[t] = pS[pr]; qA[t] = qS[pr]; cA[t] = cS[pr]; sA[t] = sS[pr];
            }
            {
                double gp[8], gq[8];
                #pragma unroll
                for (int t = 0; t < 8; ++t) { gp[t] = G[pA[t]][lane]; gq[t] = G[qA[t]][lane]; }
                #pragma unroll
                for (int t = 0; t < 8; ++t) {
                    G[pA[t]][lane] = cA[t] * gp[t] - sA[t] * gq[t];
                    G[qA[t]][lane] = sA[t] * gp[t] + cA[t] * gq[t];
                }
            }
            __syncthreads();
            {
                double gp[8], gq[8], vp[8], vq[8];
                #pragma unroll
                for (int t = 0; t < 8; ++t) { gp[t] = G[lane][pA[t]]; gq[t] = G[lane][qA[t]]; }
                #pragma unroll
                for (int t = 0; t < 8; ++t) { vp[t] = V[lane][pA[t]]; vq[t] = V[lane][qA[t]]; }
                #pragma unroll
                for (int t = 0; t < 8; ++t) {
                    G[lane][pA[t]] = cA[t] * gp[t] - sA[t] * gq[t];
                    G[lane][qA[t]] = sA[t] * gp[t] + cA[t] * gq[t];
                }
                #pragma unroll
                for (int t = 0; t < 8; ++t) {
                    V[lane][pA[t]] = cA[t] * vp[t] - sA[t] * vq[t];
                    V[lane][qA[t]] = sA[t] * vp[t] + cA[t] * vq[t];
                }
            }
            __syncthreads();
        }
    }
    if (tid == 0) {
        double lm = 0.0;
        for (int j = 0; j < 64; ++j) lm = fmax(lm, G[j][j]);
        lmaxS = lm;
    }
    __syncthreads();
    if (tid < 64) {
        const double rc = 7.62939453125e-5;
        double cut = rc * rc * lmaxS;
        double l = G[tid][tid];
        wS[tid] = (l > cut) ? (1.0 / l) : 0.0;
    }
    __syncthreads();
    for (int e = tid; e < 4096; e += 256) {
        int i = e >> 6, j = e & 63;
        double s = 0.0;
        for (int m = 0; m < 64; ++m) s += V[i][m] * wS[m] * V[j][m];
        G[i][j] = s;
    }
    __syncthreads();
    for (int e = tid; e < 4096; e += 256) {
        int i = e >> 6, j = e & 63;
        double s = 0.0;
        for (int m = 0; m < 64; ++m) s += G[i][m] * A[j][m];
        k2inv[(size_t)bh * 4096 + e] = s;
    }
}

// ---------------------------------------------------------------------------
// K5: s3_U — U = P3 @ xn.  Spill-free, conflict-free LDS.  LDS 35,584 B.
// grid (NS_, 32, 4), 256 thr.
// ---------------------------------------------------------------------------
__global__ __launch_bounds__(256)
void s3_u_kernel(const float* __restrict__ qlf, const float* __restrict__ k,
                 const float* __restrict__ X1, const float* __restrict__ stats,
                 const float* __restrict__ g1, const float* __restrict__ b1,
                 float* __restrict__ Up, float* __restrict__ sp)
{
    const int s = blockIdx.x;
    const int bh = blockIdx.y;
    const int dq = blockIdx.z;
    const int tid = threadIdx.x;
    const int b = bh >> 3;
    __shared__ float qlS[64][68];
    __shared__ float kS[16][68];
    __shared__ float S[64][17];
    __shared__ float xnS[16][132];
    __shared__ float gS[128], bS[128];
    const size_t kbase = (size_t)bh * N_ * HD_;
    const int f0 = dq * 128;

    for (int i = tid; i < 4096; i += 256) qlS[i >> 6][i & 63] = qlf[(size_t)bh * 4096 + i];
    if (tid < 128) { gS[tid] = g1[f0 + tid]; bS[tid] = b1[f0 + tid]; }

    const int lp = tid >> 3;
    const int fq = tid & 7;
    f32x4 acc0[4], acc1[4];
    #pragma unroll
    for (int j = 0; j < 4; ++j) { acc0[j] = (f32x4){0,0,0,0}; acc1[j] = (f32x4){0,0,0,0}; }
    float sacc0 = 0.f, sacc1 = 0.f;

    const int nchunks = (N_ / NS_) / 16;
    for (int c = 0; c < nchunks; ++c) {
        const int n0 = s * (N_ / NS_) + c * 16;
        __syncthreads();
        {
            int i = tid * 4;
            int n = i >> 6, d = i & 63;
            float4 v = *(const float4*)(k + kbase + (size_t)(n0 + n) * HD_ + d);
            kS[n][d + 0] = v.x; kS[n][d + 1] = v.y; kS[n][d + 2] = v.z; kS[n][d + 3] = v.w;
        }
        {
            int i = tid * 8;
            int r = i >> 7, fl = i & 127;
            int gm = b * N_ + n0 + r;
            float mean = stats[gm * 2], rs = stats[gm * 2 + 1];
            const float* xp = X1 + (size_t)gm * 512 + f0 + fl;
            float4 v0 = *(const float4*)(xp);
            float4 v1 = *(const float4*)(xp + 4);
            float xv[8] = {v0.x, v0.y, v0.z, v0.w, v1.x, v1.y, v1.z, v1.w};
            #pragma unroll
            for (int e = 0; e < 8; ++e) {
                int f = fl + e;
                float val = (xv[e] - mean) * rs * gS[f] + bS[f];
                int g = f >> 2;
                int slot = ((g & 3) << 3) | (g >> 2);
                xnS[r][slot * 4 + (f & 3)] = val;
            }
        }
        __syncthreads();
        {
            const int n = tid & 15;
            const int l0 = (tid >> 4) << 2;
            const f32x4* kr4 = (const f32x4*)&kS[n][0];
            const f32x4* q0 = (const f32x4*)&qlS[l0 + 0][0];
            const f32x4* q1 = (const f32x4*)&qlS[l0 + 1][0];
            const f32x4* q2 = (const f32x4*)&qlS[l0 + 2][0];
            const f32x4* q3 = (const f32x4*)&qlS[l0 + 3][0];
            float s0 = 0.f, s1 = 0.f, s2 = 0.f, s3 = 0.f;
            #pragma unroll
            for (int d4 = 0; d4 < 16; ++d4) {
                f32x4 kv = kr4[d4];
                f32x4 a0 = q0[d4], a1 = q1[d4], a2 = q2[d4], a3 = q3[d4];
                s0 += a0.x * kv.x + a0.y * kv.y + a0.z * kv.z + a0.w * kv.w;
                s1 += a1.x * kv.x + a1.y * kv.y + a1.z * kv.z + a1.w * kv.w;
                s2 += a2.x * kv.x + a2.y * kv.y + a2.z * kv.z + a2.w * kv.w;
                s3 += a3.x * kv.x + a3.y * kv.y + a3.z * kv.z + a3.w * kv.w;
            }
            S[l0 + 0][n] = expf(s0 * SCALE_);
            S[l0 + 1][n] = expf(s1 * SCALE_);
            S[l0 + 2][n] = expf(s2 * SCALE_);
            S[l0 + 3][n] = expf(s3 * SCALE_);
        }
        __syncthreads();
        for (int n = 0; n < 16; ++n) {
            float p0 = S[2 * lp + 0][n];
            float p1 = S[2 * lp + 1][n];
            const f32x4* xr = (const f32x4*)&xnS[n][0];
            #pragma unroll
            for (int j = 0; j < 4; ++j) {
                f32x4 xv = xr[fq + 8 * j];
                acc0[j].x += p0 * xv.x; acc0[j].y += p0 * xv.y;
                acc0[j].z += p0 * xv.z; acc0[j].w += p0 * xv.w;
                acc1[j].x += p1 * xv.x; acc1[j].y += p1 * xv.y;
                acc1[j].z += p1 * xv.z; acc1[j].w += p1 * xv.w;
            }
            if (dq == 0 && fq == 0) { sacc0 += p0; sacc1 += p1; }
        }
    }
    {
        size_t ubase = (((size_t)bh * NS_ + s) * 64) * 512;
        float4* u0 = (float4*)(Up + ubase + (size_t)(2 * lp + 0) * 512 + f0 + fq * 16);
        float4* u1 = (float4*)(Up + ubase + (size_t)(2 * lp + 1) * 512 + f0 + fq * 16);
        #pragma unroll
        for (int j = 0; j < 4; ++j) {
            u0[j] = (float4){acc0[j].x, acc0[j].y, acc0[j].z, acc0[j].w};
            u1[j] = (float4){acc1[j].x, acc1[j].y, acc1[j].z, acc1[j].w};
        }
    }
    if (dq == 0 && fq == 0) {
        sp[((size_t)bh * NS_ + s) * 64 + 2 * lp + 0] = sacc0;
        sp[((size_t)bh * NS_ + s) * 64 + 2 * lp + 1] = sacc1;
    }
}

// ---------------------------------------------------------------------------
// K6a: Un = (sum_s Up) / denom.  grid 32.
// ---------------------------------------------------------------------------
__global__ __launch_bounds__(256)
void combine_u_kernel(const float* __restrict__ Up, const float* __restrict__ sp,
                      float* __restrict__ Un)
{
    const int bh = blockIdx.x, tid = threadIdx.x;
    __shared__ float dro[64];
    if (tid < 64) {
        float d = 0.f;
        for (int s = 0; s < NS_; ++s) d += sp[((size_t)bh * NS_ + s) * 64 + tid];
        dro[tid] = d;
    }
    __syncthreads();
    for (int i = tid; i < 64 * 512; i += 256) {
        int l = i >> 9;
        float a = 0.f;
        for (int s = 0; s < NS_; ++s) a += Up[(((size_t)bh * NS_ + s) * 64) * 512 + i];
        Un[(size_t)bh * 64 * 512 + i] = a / dro[l];
    }
}

// ---------------------------------------------------------------------------
// K6b: Tn = Un @ Wv_head^T + bv.  grid 32.
// ---------------------------------------------------------------------------
__global__ __launch_bounds__(256)
void tn_kernel(const float* __restrict__ Un, const float* __restrict__ qkvw,
               const float* __restrict__ qkvb, float* __restrict__ Tn)
{
    const int bh = blockIdx.x, tid = threadIdx.x;
    const int h = bh & 7;
    const int l = tid >> 2, d0 = (tid & 3) * 16;
    const float* un = Un + (size_t)bh * 64 * 512 + l * 512;
    for (int j = 0; j < 16; ++j) {
        int d = d0 + j;
        const float* wv = qkvw + (size_t)(1024 + h * 64 + d) * 512;
        float t = 0.f;
        for (int f = 0; f < 512; ++f) t += un[f] * wv[f];
        Tn[(size_t)bh * 4096 + l * 64 + d] = t + qkvb[1024 + h * 64 + d];
    }
}

// ---------------------------------------------------------------------------
// K6c: W2 = k2pinv @ Tn.  grid 32.  LDS 16 KB.
// ---------------------------------------------------------------------------
__global__ __launch_bounds__(256)
void combine_b_kernel(const float* __restrict__ Tn, const double* __restrict__ k2inv,
                      float* __restrict__ W2)
{
    const int bh = blockIdx.x, tid = threadIdx.x;
    __shared__ float Tl[64][64];
    for (int i = tid; i < 4096; i += 256) Tl[i >> 6][i & 63] = Tn[(size_t)bh * 4096 + i];
    __syncthreads();
    const int l = tid >> 2, d0 = (tid & 3) * 16;
    float o[16];
    #pragma unroll
    for (int j = 0; j < 16; ++j) o[j] = 0.f;
    const double* kr = k2inv + (size_t)bh * 4096 + l * 64;
    for (int j2 = 0; j2 < 64; ++j2) {
        float a = (float)kr[j2];
        const float* tr = &Tl[j2][d0];
        #pragma unroll
        for (int j = 0; j < 16; ++j) o[j] += a * tr[j];
    }
    float* wp = W2 + (size_t)bh * 4096 + l * 64 + d0;
    #pragma unroll
    for (int j = 0; j < 16; ++j) wp[j] = o[j];
}

// ---------------------------------------------------------------------------
// K7: att = softmax(q·kl^T/8) @ W2 -> bf16 hi/lo.  LDS 32768 B.
// ---------------------------------------------------------------------------
__global__ __launch_bounds__(256)
void k1pv_kernel(const float* __restrict__ q, const float* __restrict__ klf,
                 const float* __restrict__ W2,
                 unsigned short* __restrict__ atth, unsigned short* __restrict__ attl)
{
    const int nc = blockIdx.x;
    const int bh = blockIdx.y;
    const int tid = threadIdx.x;
    __shared__ float klS[64][64];
    __shared__ float W2S[64][64];
    const size_t base = (size_t)bh * N_ * HD_;
    for (int i = tid; i < 4096; i += 256) {
        klS[i >> 6][i & 63] = klf[(size_t)bh * 4096 + i];
        W2S[i >> 6][i & 63] = W2[(size_t)bh * 4096 + i];
    }
    __syncthreads();
    const int n = nc * 256 + tid;
    float qf[64];
    const float4* qr = (const float4*)(q + base + (size_t)n * HD_);
    #pragma unroll
    for (int j = 0; j < 16; ++j) { float4 u = qr[j]; qf[j*4]=u.x; qf[j*4+1]=u.y; qf[j*4+2]=u.z; qf[j*4+3]=u.w; }
    float s[64];
    #pragma unroll
    for (int l = 0; l < 64; ++l) {
        const f32x4* kl4 = (const f32x4*)&klS[l][0];
        float t = 0.f;
        #pragma unroll
        for (int d4 = 0; d4 < 16; ++d4) {
            f32x4 w4 = kl4[d4];
            t += w4.x * qf[d4*4] + w4.y * qf[d4*4+1] + w4.z * qf[d4*4+2] + w4.w * qf[d4*4+3];
        }
        s[l] = t * SCALE_;
    }
    float mx = -1e30f;
    #pragma unroll
    for (int l = 0; l < 64; ++l) mx = fmaxf(mx, s[l]);
    float sum = 0.f;
    #pragma unroll
    for (int l = 0; l < 64; ++l) { s[l] = expf(s[l] - mx); sum += s[l]; }
    float inv = 1.f / sum;
    float acc[64];
    #pragma unroll
    for (int d2 = 0; d2 < 64; ++d2) acc[d2] = 0.f;
    #pragma unroll
    for (int l = 0; l < 64; ++l) {
        float p = s[l] * inv;
        const f32x4* w4p = (const f32x4*)&W2S[l][0];
        #pragma unroll
        for (int d4 = 0; d4 < 16; ++d4) {
            f32x4 w4 = w4p[d4];
            acc[d4*4+0] += p * w4.x; acc[d4*4+1] += p * w4.y;
            acc[d4*4+2] += p * w4.z; acc[d4*4+3] += p * w4.w;
        }
    }
    unsigned short* oh = atth + base + (size_t)n * HD_;
    unsigned short* ol = attl + base + (size_t)n * HD_;
    #pragma unroll
    for (int j = 0; j < 8; ++j) {
        float hv[8], lv[8];
        #pragma unroll
        for (int e = 0; e < 8; ++e) {
            float a = acc[j * 8 + e];
            unsigned short hb = f2bf(a);
            hv[e] = bf2f(hb);
            lv[e] = a - hv[e];
        }
        uint4 uh, ul;
        uh.x = pk2(hv[0], hv[1]); uh.y = pk2(hv[2], hv[3]);
        uh.z = pk2(hv[4], hv[5]); uh.w = pk2(hv[6], hv[7]);
        ul.x = pk2(lv[0], lv[1]); ul.y = pk2(lv[2], lv[3]);
        ul.z = pk2(lv[4], lv[5]); ul.w = pk2(lv[6], lv[7]);
        ((uint4*)oh)[j] = uh;
        ((uint4*)ol)[j] = ul;
    }
}

// ---------------------------------------------------------------------------
// K8: proj GEMM — split-precision MFMA (3-pass bf16 hi/lo), 128x64, BK=32.
// ---------------------------------------------------------------------------
__global__ __launch_bounds__(256)
void gemm_proj(const unsigned short* __restrict__ Aa, const unsigned short* __restrict__ Ab,
               const unsigned short* __restrict__ Wh, const unsigned short* __restrict__ Wl,
               const float* __restrict__ bias, float* __restrict__ fo0)
{
    __shared__ __align__(16) char AsH[8192];
    __shared__ __align__(16) char AsL[8192];
    __shared__ __align__(16) char BsH[4096];
    __shared__ __align__(16) char BsL[4096];
    const int tid = threadIdx.x;
    const int wv = tid >> 6, lane = tid & 63;
    const int wm = wv >> 1, wn = wv & 1;
    const int n0 = blockIdx.x * 64;
    const int m0 = blockIdx.y * 128;

    f32x4 acc[4][2];
    #pragma unroll
    for (int i = 0; i < 4; ++i)
        #pragma unroll
        for (int j = 0; j < 2; ++j) acc[i][j] = (f32x4){0.f, 0.f, 0.f, 0.f};

    for (int k0 = 0; k0 < 512; k0 += 32) {
        {
            int row = wv * 16 + (lane >> 2);
            int sl = lane & 3;
            int kk = k0 + ((sl ^ (row & 3)) << 3);
            const unsigned short* s0 = Wh + (size_t)(n0 + row) * 512 + kk;
            __builtin_amdgcn_global_load_lds((const u32g*)s0, (u32l*)(BsH + wv * 1024), 16, 0, 0);
            const unsigned short* s1 = Wl + (size_t)(n0 + row) * 512 + kk;
            __builtin_amdgcn_global_load_lds((const u32g*)s1, (u32l*)(BsL + wv * 1024), 16, 0, 0);
        }
        #pragma unroll
        for (int t = 0; t < 2; ++t) {
            int row = wv * 32 + t * 16 + (lane >> 2);
            int sl = lane & 3;
            int kk = k0 + ((sl ^ (row & 3)) << 3);
            int m = m0 + row;
            int b = m / N_; int n = m - b * N_; int hh = kk >> 6; int dd = kk & 63;
            size_t adr = (((size_t)b * NH_ + hh) * N_ + n) * HD_ + dd;
            __builtin_amdgcn_global_load_lds((const u32g*)(Aa + adr),
                                             (u32l*)(AsH + wv * 2048 + t * 1024), 16, 0, 0);
            __builtin_amdgcn_global_load_lds((const u32g*)(Ab + adr),
                                             (u32l*)(AsL + wv * 2048 + t * 1024), 16, 0, 0);
        }
        __syncthreads();
        bf16x8 afh[4], afl[4], bfh[2], bfl[2];
        #pragma unroll
        for (int mf = 0; mf < 4; ++mf) {
            int r = wm * 64 + mf * 16 + (lane & 15);
            int ps = (lane >> 4) ^ (r & 3);
            afh[mf] = *(const bf16x8*)(AsH + r * 64 + ps * 16);
            afl[mf] = *(const bf16x8*)(AsL + r * 64 + ps * 16);
        }
        #pragma unroll
        for (int nf = 0; nf < 2; ++nf) {
            int r = wn * 32 + nf * 16 + (lane & 15);
            int ps = (lane >> 4) ^ (r & 3);
            bfh[nf] = *(const bf16x8*)(BsH + r * 64 + ps * 16);
            bfl[nf] = *(const bf16x8*)(BsL + r * 64 + ps * 16);
        }
        #pragma unroll
        for (int mf = 0; mf < 4; ++mf)
            #pragma unroll
            for (int nf = 0; nf < 2; ++nf) {
                acc[mf][nf] = __builtin_amdgcn_mfma_f32_16x16x32_bf16(afh[mf], bfh[nf], acc[mf][nf], 0, 0, 0);
                acc[mf][nf] = __builtin_amdgcn_mfma_f32_16x16x32_bf16(afh[mf], bfl[nf], acc[mf][nf], 0, 0, 0);
                acc[mf][nf] = __builtin_amdgcn_mfma_f32_16x16x32_bf16(afl[mf], bfh[nf], acc[mf][nf], 0, 0, 0);
            }
        __syncthreads();
    }

    const int lc = lane & 15, lr4 = (lane >> 4) * 4;
    float bcol[2];
    #pragma unroll
    for (int nf = 0; nf < 2; ++nf)
        bcol[nf] = bias[n0 + wn * 32 + nf * 16 + lc];

    #pragma unroll
    for (int mf = 0; mf < 4; ++mf) {
        #pragma unroll
        for (int nf = 0; nf < 2; ++nf) {
            #pragma unroll
            for (int i = 0; i < 4; ++i) {
                int gm = m0 + wm * 64 + mf * 16 + lr4 + i;
                int gn = n0 + wn * 32 + nf * 16 + lc;
                fo0[(size_t)gm * 512 + gn] = acc[mf][nf][i] + bcol[nf];
            }
        }
    }
}

// ---------------------------------------------------------------------------
// K9: resid — x2 = x1 + pjo (in-place on pjo); xn2 = bf16(LN(x2, norm2)).
// ---------------------------------------------------------------------------
__global__ __launch_bounds__(256)
void resid_ln_kernel(const float* __restrict__ x1, float* __restrict__ pjo_x2,
                     const float* __restrict__ g, const float* __restrict__ bb,
                     unsigned short* __restrict__ xn2h)
{
    const int row = blockIdx.x, tid = threadIdx.x;
    const size_t base = (size_t)row * D_;
    float a0 = x1[base + tid]       + pjo_x2[base + tid];
    float a1 = x1[base + 256 + tid] + pjo_x2[base + 256 + tid];
    __shared__ float red[2][4];
    float sv = a0 + a1, sq = a0 * a0 + a1 * a1;
    #pragma unroll
    for (int o = 32; o > 0; o >>= 1) { sv += __shfl_down(sv, o); sq += __shfl_down(sq, o); }
    if ((tid & 63) == 0) { red[0][tid >> 6] = sv; red[1][tid >> 6] = sq; }
    __syncthreads();
    float tot = 0.f, totq = 0.f;
    #pragma unroll
    for (int i = 0; i < 4; ++i) { tot += red[0][i]; totq += red[1][i]; }
    float mean = tot * (1.f / 512.f);
    float var  = totq * (1.f / 512.f) - mean * mean;
    float rs = rsqrtf(var + 1e-5f);
    float o0 = (a0 - mean) * rs * g[tid]       + bb[tid];
    float o1 = (a1 - mean) * rs * g[256 + tid] + bb[256 + tid];
    pjo_x2[base + tid] = a0;
    pjo_x2[base + 256 + tid] = a1;
    xn2h[base + tid] = f2bf(o0);
    xn2h[base + 256 + tid] = f2bf(o1);
}

// ---------------------------------------------------------------------------
// K10: plain bf16 MFMA GEMM (MLP), 128x128 tile, BK=64.  LDS 32768 B.
// ---------------------------------------------------------------------------
#define E_GELU 0
#define E_ACC 1
#define E_FIN 2

template<int KLEN, int ALDA, int WLDA, int EPI, int OSTR>
__global__ __launch_bounds__(256)
void gemm_plain(const unsigned short* __restrict__ Aa,
                const unsigned short* __restrict__ Wh,
                int wrow0, int wcol0,
                const float* __restrict__ bias, int bias0,
                unsigned short* __restrict__ bo0, float* __restrict__ fo0,
                const unsigned short* __restrict__ accb, const float* __restrict__ resid)
{
    __shared__ __align__(16) char As[16384];
    __shared__ __align__(16) char Bs[16384];
    const int tid = threadIdx.x;
    const int wv = tid >> 6, lane = tid & 63;
    const int wm = wv >> 1, wn = wv & 1;
    const int n0 = blockIdx.x * 128;
    const int m0 = blockIdx.y * 128;
    const int rl = lane >> 3, sl = lane & 7;

    f32x4 acc[4][4];
    #pragma unroll
    for (int i = 0; i < 4; ++i)
        #pragma unroll
        for (int j = 0; j < 4; ++j) acc[i][j] = (f32x4){0.f, 0.f, 0.f, 0.f};

    for (int k0 = 0; k0 < KLEN; k0 += 64) {
        #pragma unroll
        for (int t = 0; t < 4; ++t) {
            int row = wv * 32 + t * 8 + rl;
            int slot = sl ^ (row & 7);
            const unsigned short* srcW = Wh + (size_t)(wrow0 + n0 + row) * WLDA + wcol0 + k0 + slot * 8;
            __builtin_amdgcn_global_load_lds((const u32g*)srcW, (u32l*)(Bs + wv * 4096 + t * 1024), 16, 0, 0);
            const unsigned short* srcA = Aa + (size_t)(m0 + row) * ALDA + k0 + slot * 8;
            __builtin_amdgcn_global_load_lds((const u32g*)srcA, (u32l*)(As + wv * 4096 + t * 1024), 16, 0, 0);
        }
        __syncthreads();
        #pragma unroll
        for (int ks = 0; ks < 2; ++ks) {
            bf16x8 af[4], bfr[4];
            #pragma unroll
            for (int mf = 0; mf < 4; ++mf) {
                int r = wm * 64 + mf * 16 + (lane & 15);
                int ps = (ks * 4 + (lane >> 4)) ^ (r & 7);
                af[mf] = *(const bf16x8*)(As + r * 128 + ps * 16);
            }
            #pragma unroll
            for (int nf = 0; nf < 4; ++nf) {
                int r = wn * 64 + nf * 16 + (lane & 15);
                int ps = (ks * 4 + (lane >> 4)) ^ (r & 7);
                bfr[nf] = *(const bf16x8*)(Bs + r * 128 + ps * 16);
            }
            #pragma unroll
            for (int mf = 0; mf < 4; ++mf)
                #pragma unroll
                for (int nf = 0; nf < 4; ++nf)
                    acc[mf][nf] = __builtin_amdgcn_mfma_f32_16x16x32_bf16(af[mf], bfr[nf], acc[mf][nf], 0, 0, 0);
        }
        __syncthreads();
    }

    const int lc = lane & 15, lr4 = (lane >> 4) * 4;
    float bcol[4];
    #pragma unroll
    for (int nf = 0; nf < 4; ++nf)
        bcol[nf] = bias ? bias[bias0 + n0 + wn * 64 + nf * 16 + lc] : 0.f;

    #pragma unroll
    for (int mf = 0; mf < 4; ++mf) {
        #pragma unroll
        for (int nf = 0; nf < 4; ++nf) {
            #pragma unroll
            for (int i = 0; i < 4; ++i) {
                int gm = m0 + wm * 64 + mf * 16 + lr4 + i;
                int gn = n0 + wn * 64 + nf * 16 + lc;
                float val = acc[mf][nf][i] + bcol[nf];
                if (EPI == E_GELU) {
                    float g = 0.5f * val * (1.f + erff(val * 0.70710678118f));
                    bo0[(size_t)gm * OSTR + gn] = f2bf(g);
                } else if (EPI == E_ACC) {
                    bo0[(size_t)gm * OSTR + gn] = f2bf(val);
                } else {
                    fo0[(size_t)gm * 512 + gn] = val + bf2f(accb[(size_t)gm * 512 + gn])
                                               + resid[(size_t)gm * 512 + gn];
                }
            }
        }
    }
}

// ---------------------------------------------------------------------------
extern "C" void kernel_launch(void* const* d_in, const int* in_sizes, int n_in,
                              void* d_out, int out_size, void* d_ws, size_t ws_size,
                              hipStream_t stream) {
    const float* x    = (const float*)d_in[0];
    const float* c1w  = (const float*)d_in[1];
    const float* c1b  = (const float*)d_in[2];
    const float* c2w  = (const float*)d_in[3];
    const float* c2b  = (const float*)d_in[4];
    const float* c3w  = (const float*)d_in[5];
    const float* c3b  = (const float*)d_in[6];
    const float* pg   = (const float*)d_in[7];
    const float* pb   = (const float*)d_in[8];
    const float* n1g  = (const float*)d_in[9];
    const float* n1b  = (const float*)d_in[10];
    const float* n2g  = (const float*)d_in[11];
    const float* n2b  = (const float*)d_in[12];
    const float* qkvw = (const float*)d_in[13];
    const float* qkvb = (const float*)d_in[14];
    const float* pjw  = (const float*)d_in[15];
    const float* pjb  = (const float*)d_in[16];
    const float* w1   = (const float*)d_in[17];
    const float* b1   = (const float*)d_in[18];
    const float* w2m  = (const float*)d_in[19];
    const float* b2m  = (const float*)d_in[20];

    char* ws = (char*)d_ws;
    char* RA = ws;
    char* RB = ws + 75497472;
    char* RC = ws + 150994944;
    char* R3 = ws + 226492416;
    unsigned short* pwh  = (unsigned short*)(R3 + 0);
    unsigned short* pwl  = (unsigned short*)(R3 + 524288);
    unsigned short* w1b  = (unsigned short*)(R3 + 1048576);
    unsigned short* w2b  = (unsigned short*)(R3 + 3145728);
    float*  stats = (float*)(R3 + 5242880);
    float*  qlf   = (float*)(R3 + 5537792);
    float*  klf   = (float*)(R3 + 6062080);
    double* ql64  = (double*)(R3 + 6586368);
    double* kl64  = (double*)(R3 + 7634944);
    double* k2i   = (double*)(R3 + 8683520);
    float*  W2    = (float*)(R3 + 9732096);
    float*  Tn    = (float*)(R3 + 10256384);
    float*  sp    = (float*)(R3 + 10780672);
    float*  Up    = (float*)(R3 + 10813440);
    float*  Un    = (float*)(R3 + 27590656);

    float* x1 = (float*)RA;
    float* kb = (float*)RB;
    float* qb = (float*)RC;
    unsigned short* atth = (unsigned short*)RB;
    unsigned short* attl = (unsigned short*)(RB + 37748736);
    float* pjo = (float*)RC;
    unsigned short* xn2  = (unsigned short*)RB;
    unsigned short* accb = (unsigned short*)(RB + 37748736);
    unsigned short* hbuf = (unsigned short*)RA;

    prep_weights<<<1024, 256, 0, stream>>>(pjw, w1, w2m, pwh, pwl, w1b, w2b);
    ppeg_ln_kernel<<<dim3(8, B_ * HH_), 512, 0, stream>>>(x, c1w, c1b, c2w, c2b, c3w, c3b,
                                                          pg, pb, x1, stats);
    gemm_f32_qk<<<dim3(8, 288), 256, 0, stream>>>(x1, stats, n1g, n1b, qkvw, qkvb, qb, kb);
    extract_lm<<<32, 256, 0, stream>>>(qb, kb, qlf, klf, ql64, kl64);
    k2pinv_kernel<<<32, 256, 0, stream>>>(ql64, kl64, k2i);
    s3_u_kernel<<<dim3(NS_, 32, 4), 256, 0, stream>>>(qlf, kb, x1, stats, n1g, n1b, Up, sp);
    combine_u_kernel<<<32, 256, 0, stream>>>(Up, sp, Un);
    tn_kernel<<<32, 256, 0, stream>>>(Un, qkvw, qkvb, Tn);
    combine_b_kernel<<<32, 256, 0, stream>>>(Tn, k2i, W2);
    k1pv_kernel<<<dim3(36, 32), 256, 0, stream>>>(qb, klf, W2, atth, attl);
    gemm_proj<<<dim3(8, 288), 256, 0, stream>>>(atth, attl, pwh, pwl, pjb, pjo);
    resid_ln_kernel<<<MT_, 256, 0, stream>>>(x1, pjo, n2g, n2b, xn2);
    gemm_plain<512, 512, 512, E_GELU, 1024><<<dim3(8, 288), 256, 0, stream>>>(
        xn2, w1b, 0, 0, b1, 0, hbuf, nullptr, nullptr, nullptr);
    gemm_plain<1024, 1024, 2048, E_ACC, 512><<<dim3(4, 288), 256, 0, stream>>>(
        hbuf, w2b, 0, 0, nullptr, 0, accb, nullptr, nullptr, nullptr);
    gemm_plain<512, 512, 512, E_GELU, 1024><<<dim3(8, 288), 256, 0, stream>>>(
        xn2, w1b, 1024, 0, b1, 1024, hbuf, nullptr, nullptr, nullptr);
    gemm_plain<1024, 1024, 2048, E_FIN, 512><<<dim3(4, 288), 256, 0, stream>>>(
        hbuf, w2b, 0, 1024, b2m, 0, nullptr, (float*)d_out, accb, pjo);
}